// Round 2
// baseline (526.985 us; speedup 1.0000x reference)
//
#include <hip/hip_runtime.h>
#include <hip/hip_bf16.h>
#include <math.h>

// Problem constants (setup_inputs: B=4, T=1024)
#define BB 4
#define TT 1024
#define BT 4096

// Workspace layout (fp32 offsets in floats)
#define OFF_BLOCKS 0          // [BT][64]  blocks in [i*4+e] channel order
#define OFF_QKVB   262144     // [16][BT][12] per-block qkv
#define OFF_ALLB   1048576    // [BT][64]  per-block MHA output (all_blocks)
#define OFF_QKVC   1310720    // [BT][192] cross qkv
#define OFF_LC     2097152    // [B*8][T]  cross softmax denominators (unnormalized)
#define OFF_ACCC   2129920    // [B*8][T][8] cross PV accumulators (unnormalized)
#define OFF_RECV   2392064    // [B][T]    attention-received column means
#define OFF_LN1    2396160    // [BT][64]  post-LN1 activations
#define OFF_FLAGS  2658304    // [16] ints: [0]=floats-are-bf16, [1]=tokens-are-int64
#define WS_FLOATS  2658320

// ---------- dtype-flexible load helpers ----------
__device__ inline float bf2f(__hip_bfloat16 v) { return __bfloat162float(v); }

__device__ inline float ldf(const void* p, int i, bool isbf) {
  return isbf ? __bfloat162float(((const __hip_bfloat16*)p)[i])
              : ((const float*)p)[i];
}

__device__ inline void bf16x8_to_f32(const __hip_bfloat16* p, float* w) {
  uint4 u = *reinterpret_cast<const uint4*>(p);
  w[0] = __uint_as_float(u.x << 16); w[1] = __uint_as_float(u.x & 0xffff0000u);
  w[2] = __uint_as_float(u.y << 16); w[3] = __uint_as_float(u.y & 0xffff0000u);
  w[4] = __uint_as_float(u.z << 16); w[5] = __uint_as_float(u.z & 0xffff0000u);
  w[6] = __uint_as_float(u.w << 16); w[7] = __uint_as_float(u.w & 0xffff0000u);
}

__device__ inline void load8_any(const void* p, int off, float* w, bool isbf) {
  if (isbf) {
    bf16x8_to_f32((const __hip_bfloat16*)p + off, w);
  } else {
    const float4* f = (const float4*)((const float*)p + off);
    float4 a = f[0], b = f[1];
    w[0]=a.x; w[1]=a.y; w[2]=a.z; w[3]=a.w; w[4]=b.x; w[5]=b.y; w[6]=b.z; w[7]=b.w;
  }
}

__device__ inline float dot8_any(const void* W, int off, const float* x, bool isbf) {
  float w[8]; load8_any(W, off, w, isbf);
  return w[0]*x[0] + w[1]*x[1] + w[2]*x[2] + w[3]*x[3]
       + w[4]*x[4] + w[5]*x[5] + w[6]*x[6] + w[7]*x[7];
}

// ---------- K0: dtype detection ----------
// bf16 N(0,1) data: every halfword's exponent field in [90,141].
// fp32 data: low halfwords have ~uniform exponent bits (pass ~20%).
__global__ void __launch_bounds__(64) k_detect(
    const void* __restrict__ M, const int* __restrict__ tok, int* __restrict__ flags) {
  const unsigned short* h = (const unsigned short*)M;
  unsigned short v = h[threadIdx.x];
  int e = (v >> 7) & 0xff;
  bool pass = (e >= 90) && (e <= 141);
  unsigned long long m = __ballot(pass);
  if (threadIdx.x == 0) {
    flags[0] = (__popcll(m) >= 58) ? 1 : 0;
    flags[1] = ((tok[1] | tok[3] | tok[5] | tok[7]) == 0) ? 1 : 0;
  }
}

// ---------- K1: blocks gather + per-block QKV (16 blocks, E=4 -> 12 chans) ----------
__global__ void __launch_bounds__(256) k_prep(
    const void* __restrict__ M,
    const void* __restrict__ Wqkv_blk,
    const void* __restrict__ bqkv_blk,
    const int* __restrict__ flags,
    float* __restrict__ blocks, float* __restrict__ qkv_blk) {
  bool isbf = flags[0];
  int g = blockIdx.x * 256 + threadIdx.x;        // 65536 = 16 blocks * 4096 tokens
  int i = g >> 12, bt = g & 4095;
  int rb = i >> 2, cb = i & 3;
  float x[4];
  #pragma unroll
  for (int r = 0; r < 2; ++r)
    #pragma unroll
    for (int c = 0; c < 2; ++c)
      x[r*2+c] = ldf(M, bt*64 + (rb*2+r)*8 + cb*2 + c, isbf);
  float* bo = blocks + bt*64 + i*4;
  #pragma unroll
  for (int j = 0; j < 4; ++j) bo[j] = x[j];
  float* o = qkv_blk + (i*BT + bt) * 12;
  #pragma unroll
  for (int c = 0; c < 12; ++c) {
    float a = ldf(bqkv_blk, i*12 + c, isbf);
    #pragma unroll
    for (int j = 0; j < 4; ++j) a += ldf(Wqkv_blk, i*48 + c*4 + j, isbf) * x[j];
    o[c] = a;
  }
}

// ---------- K2: per-block attention (H=2, Dh=2), K/V in LDS, + Wo projection ----------
__global__ void __launch_bounds__(256) k_blk_attn(
    const float* __restrict__ qkv_blk,
    const void* __restrict__ Wo_blk,
    const void* __restrict__ bo_blk,
    const int* __restrict__ flags,
    float* __restrict__ all_blocks) {
  __shared__ float kv[1024*8];     // [key][kc0 kc1 kc2 kc3 vc0 vc1 vc2 vc3]
  __shared__ float tmp[128*4];
  bool isbf = flags[0];
  int bid = blockIdx.x;            // grid 512 = 16i * 4b * 8qt
  int qt = bid & 7, b = (bid >> 3) & 3, i = bid >> 5;
  const float* base = qkv_blk + (i*BT + b*TT) * 12;
  for (int idx = threadIdx.x; idx < 8192; idx += 256) {
    int row = idx >> 3, c = idx & 7;
    kv[idx] = base[row*12 + 4 + c];
  }
  __syncthreads();
  int h = threadIdx.x >> 7, ql = threadIdx.x & 127;   // h wave-uniform
  int q = qt*128 + ql;
  float q0 = base[q*12 + h*2]     * 0.70710678f;      // 1/sqrt(Dh=2)
  float q1 = base[q*12 + h*2 + 1] * 0.70710678f;
  float l = 0.f, a0 = 0.f, a1 = 0.f;
  #pragma unroll 4
  for (int k = 0; k < 1024; ++k) {
    const float* kr = kv + k*8 + h*2;
    float s = q0*kr[0] + q1*kr[1];
    float p = __expf(s);
    l  += p;
    a0 += p * kr[4];
    a1 += p * kr[5];
  }
  float inv = 1.f / l;
  tmp[ql*4 + h*2]     = a0 * inv;
  tmp[ql*4 + h*2 + 1] = a1 * inv;
  __syncthreads();
  if (threadIdx.x < 128) {
    int qq = qt*128 + threadIdx.x;
    float o[4];
    #pragma unroll
    for (int m2 = 0; m2 < 4; ++m2) o[m2] = tmp[threadIdx.x*4 + m2];
    float* outp = all_blocks + (b*TT + qq)*64 + i*4;
    #pragma unroll
    for (int j = 0; j < 4; ++j) {
      float a = ldf(bo_blk, i*4 + j, isbf);
      #pragma unroll
      for (int m2 = 0; m2 < 4; ++m2) a += ldf(Wo_blk, i*16 + j*4 + m2, isbf) * o[m2];
      outp[j] = a;
    }
  }
}

// ---------- K3: cross QKV projection (64 -> 192) ----------
__global__ void __launch_bounds__(256) k_qkv_c(
    const float* __restrict__ all_blocks,
    const void* __restrict__ Wqkv_c,
    const void* __restrict__ bqkv_c,
    const int* __restrict__ flags,
    float* __restrict__ qkv_c) {
  __shared__ float xs[8*64];
  bool isbf = flags[0];
  int t0 = blockIdx.x * 8;         // grid 512
  for (int idx = threadIdx.x; idx < 512; idx += 256)
    xs[idx] = all_blocks[t0*64 + idx];
  __syncthreads();
  int tok = threadIdx.x >> 5, lane32 = threadIdx.x & 31;
  const float* x = xs + tok*64;
  #pragma unroll
  for (int kk = 0; kk < 6; ++kk) {
    int c = kk*32 + lane32;
    float a = ldf(bqkv_c, c, isbf);
    #pragma unroll
    for (int j = 0; j < 64; j += 8) a += dot8_any(Wqkv_c, c*64 + j, x + j, isbf);
    qkv_c[(t0 + tok)*192 + c] = a;
  }
}

// ---------- K4: cross attention partials (key-split x2), unnormalized l / acc ----------
__global__ void __launch_bounds__(64) k_cross_attn(
    const float* __restrict__ qkv_c,
    float* __restrict__ l_c, float* __restrict__ acc_c) {
  __shared__ float kv[512*16];     // [key][k0..k7 v0..v7]
  int bid = blockIdx.x;            // grid 1024 = 4b * 8h * 16qt * 2ks
  int ks = bid & 1, qt = (bid >> 1) & 15, h = (bid >> 5) & 7, b = bid >> 8;
  const float* base = qkv_c + b*TT*192;
  for (int idx = threadIdx.x; idx < 8192; idx += 64) {
    int row = idx >> 4, c = idx & 15;
    int chan = (c < 8) ? (64 + h*8 + c) : (120 + h*8 + c);  // k chans / v chans
    kv[idx] = base[(ks*512 + row)*192 + chan];
  }
  __syncthreads();
  int q = qt*64 + threadIdx.x;
  float qv[8];
  #pragma unroll
  for (int c = 0; c < 8; ++c) qv[c] = base[q*192 + h*8 + c] * 0.35355339f; // 1/sqrt(8)
  float l = 0.f, acc[8];
  #pragma unroll
  for (int c = 0; c < 8; ++c) acc[c] = 0.f;
  #pragma unroll 2
  for (int k = 0; k < 512; ++k) {
    const float* kr = kv + k*16;
    float s = 0.f;
    #pragma unroll
    for (int c = 0; c < 8; ++c) s += qv[c] * kr[c];
    float p = __expf(s);
    l += p;
    #pragma unroll
    for (int c = 0; c < 8; ++c) acc[c] += p * kr[8 + c];
  }
  int base_o = (b*8 + h)*TT + q;
  atomicAdd(l_c + base_o, l);
  #pragma unroll
  for (int c = 0; c < 8; ++c) atomicAdd(acc_c + base_o*8 + c, acc[c]);
}

// ---------- K5: normalize PV, Wo_c projection, residual, LN1 ----------
__global__ void __launch_bounds__(256) k_finalize_cross(
    const float* __restrict__ all_blocks,
    const float* __restrict__ l_c, const float* __restrict__ acc_c,
    const void* __restrict__ Wo_c, const void* __restrict__ bo_c,
    const void* __restrict__ g1, const void* __restrict__ be1,
    const int* __restrict__ flags,
    float* __restrict__ ln1) {
  __shared__ float pvs[4*64];
  bool isbf = flags[0];
  int tt = threadIdx.x >> 6, j = threadIdx.x & 63;  // one token per wave, lane = channel
  int t = blockIdx.x*4 + tt;       // grid 1024
  int b = t >> 10, tl = t & 1023;
  int h = j >> 3;
  int idx = (b*8 + h)*TT + tl;
  pvs[tt*64 + j] = acc_c[idx*8 + (j & 7)] / l_c[idx];
  __syncthreads();
  float a = ldf(bo_c, j, isbf);
  const float* p = pvs + tt*64;
  #pragma unroll
  for (int m = 0; m < 64; m += 8) a += dot8_any(Wo_c, j*64 + m, p + m, isbf);
  float x = all_blocks[t*64 + j] + a;
  float s = x, s2 = x*x;
  #pragma unroll
  for (int off = 32; off; off >>= 1) { s += __shfl_xor(s, off); s2 += __shfl_xor(s2, off); }
  float mu  = s  * (1.f/64.f);
  float var = s2 * (1.f/64.f) - mu*mu;
  float y = (x - mu) * rsqrtf(var + 1e-5f) * ldf(g1, j, isbf) + ldf(be1, j, isbf);
  ln1[t*64 + j] = y;
}

// ---------- K6: attention-received column means (needs final l from K4) ----------
__global__ void __launch_bounds__(64) k_recv(
    const float* __restrict__ qkv_c,
    const float* __restrict__ l_c,
    float* __restrict__ attn_recv) {
  __shared__ float kk[1024*9];     // stride 9 -> conflict-free strided lane access
  __shared__ float col[1024];
  int bid = blockIdx.x;            // grid 512 = 4b * 8h * 16qt
  int qt = bid & 15, h = (bid >> 4) & 7, b = bid >> 7;
  const float* base = qkv_c + b*TT*192;
  for (int idx = threadIdx.x; idx < 8192; idx += 64) {
    int row = idx >> 3, c = idx & 7;
    kk[row*9 + c] = base[row*192 + 64 + h*8 + c];
  }
  for (int k = threadIdx.x; k < 1024; k += 64) col[k] = 0.f;
  __syncthreads();
  int q = qt*64 + threadIdx.x;
  float qv[8];
  #pragma unroll
  for (int c = 0; c < 8; ++c) qv[c] = base[q*192 + h*8 + c] * 0.35355339f;
  float invl = 1.f / l_c[(b*8 + h)*TT + q];
  for (int jj = 0; jj < 1024; ++jj) {
    int k = (jj + threadIdx.x) & 1023;     // staggered: lanes hit distinct addresses
    const float* kr = kk + k*9;
    float s = 0.f;
    #pragma unroll
    for (int c = 0; c < 8; ++c) s += qv[c] * kr[c];
    atomicAdd(col + k, __expf(s) * invl);
  }
  __syncthreads();
  for (int k = threadIdx.x; k < 1024; k += 64)
    atomicAdd(attn_recv + b*TT + k, col[k] * (1.f/8192.f));  // /(H=8 * T=1024)
}

// ---------- K7: FFN + LN2 + sensitivity gate + un-blocking to 8x8 ----------
__global__ void __launch_bounds__(256) k_ffn_out(
    const float* __restrict__ ln1,
    const void* __restrict__ W1b, const void* __restrict__ b1b,
    const void* __restrict__ W2b, const void* __restrict__ b2b,
    const void* __restrict__ g2, const void* __restrict__ be2,
    const float* __restrict__ blocks,
    const int* __restrict__ tok32,
    const float* __restrict__ attn_recv,
    const void* __restrict__ sens_emb,
    const void* __restrict__ sens_alpha,
    const int* __restrict__ flags,
    void* __restrict__ out) {
  __shared__ float ld[4*64];
  __shared__ float hbuf[4*256];
  bool isbf = flags[0];
  int t0 = blockIdx.x * 4;         // grid 1024, 4 tokens per WG
  ld[threadIdx.x] = ln1[t0*64 + threadIdx.x];
  __syncthreads();
  // phase 1: hidden = gelu(ln1 @ W1^T + b1), one hidden unit per thread x 4 tokens
  {
    float acc[4];
    float bb = ldf(b1b, threadIdx.x, isbf);
    #pragma unroll
    for (int tt = 0; tt < 4; ++tt) acc[tt] = bb;
    #pragma unroll
    for (int j = 0; j < 64; j += 8) {
      float w[8]; load8_any(W1b, threadIdx.x*64 + j, w, isbf);
      #pragma unroll
      for (int jj = 0; jj < 8; ++jj)
        #pragma unroll
        for (int tt = 0; tt < 4; ++tt) acc[tt] += w[jj] * ld[tt*64 + j + jj];
    }
    #pragma unroll
    for (int tt = 0; tt < 4; ++tt) {
      float v = acc[tt];
      hbuf[tt*256 + threadIdx.x] = 0.5f * v * (1.f + erff(v * 0.70710678f));
    }
  }
  __syncthreads();
  // phase 2: y = hidden @ W2^T + b2; residual; LN2; gate; un-block
  int tt = threadIdx.x >> 6, j = threadIdx.x & 63;   // token per wave, lane = channel
  int t = t0 + tt, b = t >> 10, tl = t & 1023;
  float y = ldf(b2b, j, isbf);
  const float* hb = hbuf + tt*256;
  #pragma unroll
  for (int k = 0; k < 256; k += 8) y += dot8_any(W2b, j*256 + k, hb + k, isbf);
  float z = ld[tt*64 + j] + y;
  float s = z, s2 = z*z;
  #pragma unroll
  for (int off = 32; off; off >>= 1) { s += __shfl_xor(s, off); s2 += __shfl_xor(s2, off); }
  float mu  = s  * (1.f/64.f);
  float var = s2 * (1.f/64.f) - mu*mu;
  float y2 = (z - mu) * rsqrtf(var + 1e-5f) * ldf(g2, j, isbf) + ldf(be2, j, isbf);
  int tok = flags[1] ? tok32[t*2] : tok32[t];
  int i = j >> 2, e = j & 3;
  float recv = attn_recv[b*TT + tl];
  float sv = ldf(sens_emb, tok*16 + i, isbf) + recv * ldf(sens_alpha, i, isbf);
  float sg = 1.f / (1.f + __expf(-sv));
  float blk = blocks[t*64 + j];
  float nb = blk + (y2 - blk) * sg;
  int rb = i >> 2, cb = i & 3, r = e >> 1, c = e & 1;
  int oidx = t*64 + (rb*2 + r)*8 + cb*2 + c;
  if (isbf) ((__hip_bfloat16*)out)[oidx] = __float2bfloat16(nb);
  else      ((float*)out)[oidx] = nb;
}

extern "C" void kernel_launch(void* const* d_in, const int* in_sizes, int n_in,
                              void* d_out, int out_size, void* d_ws, size_t ws_size,
                              hipStream_t stream) {
  const void* M        = d_in[0];
  const int*  tok      = (const int*)d_in[1];
  const void* Wqkv_blk = d_in[2];
  const void* bqkv_blk = d_in[3];
  const void* Wo_blk   = d_in[4];
  const void* bo_blk   = d_in[5];
  const void* Wqkv_c   = d_in[6];
  const void* bqkv_c   = d_in[7];
  const void* Wo_c     = d_in[8];
  const void* bo_c     = d_in[9];
  const void* W1       = d_in[10];
  const void* b1       = d_in[11];
  const void* W2       = d_in[12];
  const void* b2       = d_in[13];
  const void* g1       = d_in[14];
  const void* be1      = d_in[15];
  const void* g2       = d_in[16];
  const void* be2      = d_in[17];
  const void* sens_emb = d_in[18];
  const void* sens_al  = d_in[19];

  float* ws = (float*)d_ws;
  float* blocks    = ws + OFF_BLOCKS;
  float* qkv_blk   = ws + OFF_QKVB;
  float* all_blk   = ws + OFF_ALLB;
  float* qkv_c     = ws + OFF_QKVC;
  float* l_c       = ws + OFF_LC;
  float* acc_c     = ws + OFF_ACCC;
  float* attn_recv = ws + OFF_RECV;
  float* ln1       = ws + OFF_LN1;
  int*   flags     = (int*)(ws + OFF_FLAGS);

  // zero the atomic accumulators (l_c, acc_c, attn_recv are contiguous)
  hipMemsetAsync(l_c, 0, (size_t)(32768 + 262144 + 4096) * sizeof(float), stream);

  k_detect<<<1, 64, 0, stream>>>(M, tok, flags);
  k_prep<<<256, 256, 0, stream>>>(M, Wqkv_blk, bqkv_blk, flags, blocks, qkv_blk);
  k_blk_attn<<<512, 256, 0, stream>>>(qkv_blk, Wo_blk, bo_blk, flags, all_blk);
  k_qkv_c<<<512, 256, 0, stream>>>(all_blk, Wqkv_c, bqkv_c, flags, qkv_c);
  k_cross_attn<<<1024, 64, 0, stream>>>(qkv_c, l_c, acc_c);
  k_finalize_cross<<<1024, 256, 0, stream>>>(all_blk, l_c, acc_c, Wo_c, bo_c, g1, be1, flags, ln1);
  k_recv<<<512, 64, 0, stream>>>(qkv_c, l_c, attn_recv);
  k_ffn_out<<<1024, 256, 0, stream>>>(ln1, W1, b1, W2, b2, g2, be2,
                                      blocks, tok, attn_recv, sens_emb, sens_al,
                                      flags, (void*)d_out);
}

// Round 4
// 403.166 us; speedup vs baseline: 1.3071x; 1.3071x over previous
//
#include <hip/hip_runtime.h>
#include <hip/hip_bf16.h>
#include <math.h>

// Problem constants (setup_inputs: B=4, T=1024)
#define BB 4
#define TT 1024
#define BT 4096

// Workspace layout (fp32 offsets in floats)
#define OFF_BLOCKS 0          // [BT][64]  blocks in [i*4+e] channel order
#define OFF_QKVB   262144     // [16][BT][12] per-block qkv (dead after k_blk_attn2)
#define OFF_RECVP  262144     // [B][1024k][128src] recv partials (aliases QKVB)
#define OFF_ALLB   1048576    // [BT][64]  per-block MHA output (all_blocks)
#define OFF_QKVC   1310720    // [BT][192] cross qkv
#define OFF_LC     2097152    // [B*8][T]  cross softmax denominators (unnormalized)
#define OFF_ACCC   2129920    // [B*8][T][8] cross PV accumulators (unnormalized)
#define OFF_RECV   2392064    // [B][T]    attention-received column means
#define OFF_LN1    2396160    // [BT][64]  post-LN1 activations
#define OFF_FLAGS  2658304    // [16] ints: [0]=floats-are-bf16, [1]=tokens-are-int64
#define WS_FLOATS  2658320

__device__ inline float rcpf(float x) { return __builtin_amdgcn_rcpf(x); }

// ---------- dtype-flexible load helpers ----------
__device__ inline float ldf(const void* p, int i, bool isbf) {
  return isbf ? __bfloat162float(((const __hip_bfloat16*)p)[i])
              : ((const float*)p)[i];
}

__device__ inline void bf16x8_to_f32(const __hip_bfloat16* p, float* w) {
  uint4 u = *reinterpret_cast<const uint4*>(p);
  w[0] = __uint_as_float(u.x << 16); w[1] = __uint_as_float(u.x & 0xffff0000u);
  w[2] = __uint_as_float(u.y << 16); w[3] = __uint_as_float(u.y & 0xffff0000u);
  w[4] = __uint_as_float(u.z << 16); w[5] = __uint_as_float(u.z & 0xffff0000u);
  w[6] = __uint_as_float(u.w << 16); w[7] = __uint_as_float(u.w & 0xffff0000u);
}

__device__ inline void load8_any(const void* p, int off, float* w, bool isbf) {
  if (isbf) {
    bf16x8_to_f32((const __hip_bfloat16*)p + off, w);
  } else {
    const float4* f = (const float4*)((const float*)p + off);
    float4 a = f[0], b = f[1];
    w[0]=a.x; w[1]=a.y; w[2]=a.z; w[3]=a.w; w[4]=b.x; w[5]=b.y; w[6]=b.z; w[7]=b.w;
  }
}

__device__ inline float dot8_any(const void* W, int off, const float* x, bool isbf) {
  float w[8]; load8_any(W, off, w, isbf);
  return w[0]*x[0] + w[1]*x[1] + w[2]*x[2] + w[3]*x[3]
       + w[4]*x[4] + w[5]*x[5] + w[6]*x[6] + w[7]*x[7];
}

// ---------- K0: dtype detection ----------
__global__ void __launch_bounds__(64) k_detect(
    const void* __restrict__ M, const int* __restrict__ tok, int* __restrict__ flags) {
  const unsigned short* h = (const unsigned short*)M;
  unsigned short v = h[threadIdx.x];
  int e = (v >> 7) & 0xff;
  bool pass = (e >= 90) && (e <= 141);
  unsigned long long m = __ballot(pass);
  if (threadIdx.x == 0) {
    flags[0] = (__popcll(m) >= 58) ? 1 : 0;
    flags[1] = ((tok[1] | tok[3] | tok[5] | tok[7]) == 0) ? 1 : 0;
  }
}

// ---------- K1: blocks gather + per-block QKV ----------
__global__ void __launch_bounds__(256) k_prep(
    const void* __restrict__ M,
    const void* __restrict__ Wqkv_blk,
    const void* __restrict__ bqkv_blk,
    const int* __restrict__ flags,
    float* __restrict__ blocks, float* __restrict__ qkv_blk) {
  bool isbf = flags[0];
  int g = blockIdx.x * 256 + threadIdx.x;        // 65536 = 16 blocks * 4096 tokens
  int i = g >> 12, bt = g & 4095;
  int rb = i >> 2, cb = i & 3;
  float x[4];
  #pragma unroll
  for (int r = 0; r < 2; ++r)
    #pragma unroll
    for (int c = 0; c < 2; ++c)
      x[r*2+c] = ldf(M, bt*64 + (rb*2+r)*8 + cb*2 + c, isbf);
  float* bo = blocks + bt*64 + i*4;
  #pragma unroll
  for (int j = 0; j < 4; ++j) bo[j] = x[j];
  float* o = qkv_blk + (i*BT + bt) * 12;
  #pragma unroll
  for (int c = 0; c < 12; ++c) {
    float a = ldf(bqkv_blk, i*12 + c, isbf);
    #pragma unroll
    for (int j = 0; j < 4; ++j) a += ldf(Wqkv_blk, i*48 + c*4 + j, isbf) * x[j];
    o[c] = a;
  }
}

// ---------- K2: per-block attention, s_load K/V (wave-uniform), both heads/thread ----------
__global__ void __launch_bounds__(64) k_blk_attn2(
    const float* __restrict__ qkv_blk,
    const void* __restrict__ Wo_blk,
    const void* __restrict__ bo_blk,
    const int* __restrict__ flags,
    float* __restrict__ all_blocks) {
  bool isbf = flags[0];
  int bid = blockIdx.x;            // grid 1024 = 16i * 4b * 16qt
  int qt = bid & 15, b = (bid >> 4) & 3, i = bid >> 6;
  const float* base = qkv_blk + (size_t)(i*BT + b*TT) * 12;
  int q = qt*64 + threadIdx.x;
  const float* qr = base + q*12;
  const float S2 = 0.70710678f;    // 1/sqrt(Dh=2)
  float q00 = qr[0]*S2, q01 = qr[1]*S2;   // head 0
  float q10 = qr[2]*S2, q11 = qr[3]*S2;   // head 1
  float l0=0.f, l1=0.f, a00=0.f, a01=0.f, a10=0.f, a11=0.f;
  #pragma unroll 4
  for (int k = 0; k < 1024; ++k) {
    const float* kr = base + k*12 + 4;    // uniform address -> SMEM
    float k0=kr[0], k1=kr[1], k2=kr[2], k3=kr[3];
    float v0=kr[4], v1=kr[5], v2=kr[6], v3=kr[7];
    float p0 = __expf(q00*k0 + q01*k1);
    float p1 = __expf(q10*k2 + q11*k3);
    l0 += p0; a00 += p0*v0; a01 += p0*v1;
    l1 += p1; a10 += p1*v2; a11 += p1*v3;
  }
  float r0 = rcpf(l0), r1 = rcpf(l1);
  float o[4] = { a00*r0, a01*r0, a10*r1, a11*r1 };
  float* outp = all_blocks + (size_t)(b*TT + q)*64 + i*4;
  #pragma unroll
  for (int j = 0; j < 4; ++j) {
    float a = ldf(bo_blk, i*4 + j, isbf);
    #pragma unroll
    for (int m2 = 0; m2 < 4; ++m2) a += ldf(Wo_blk, i*16 + j*4 + m2, isbf) * o[m2];
    outp[j] = a;
  }
}

// ---------- K3: cross QKV projection (64 -> 192) ----------
__global__ void __launch_bounds__(256) k_qkv_c(
    const float* __restrict__ all_blocks,
    const void* __restrict__ Wqkv_c,
    const void* __restrict__ bqkv_c,
    const int* __restrict__ flags,
    float* __restrict__ qkv_c) {
  __shared__ float xs[8*64];
  bool isbf = flags[0];
  int t0 = blockIdx.x * 8;         // grid 512
  for (int idx = threadIdx.x; idx < 512; idx += 256)
    xs[idx] = all_blocks[t0*64 + idx];
  __syncthreads();
  int tok = threadIdx.x >> 5, lane32 = threadIdx.x & 31;
  const float* x = xs + tok*64;
  #pragma unroll
  for (int kk = 0; kk < 6; ++kk) {
    int c = kk*32 + lane32;
    float a = ldf(bqkv_c, c, isbf);
    #pragma unroll
    for (int j = 0; j < 64; j += 8) a += dot8_any(Wqkv_c, c*64 + j, x + j, isbf);
    qkv_c[(t0 + tok)*192 + c] = a;
  }
}

// ---------- K4: cross attention partials, s_load K/V, key-split x4 ----------
__global__ void __launch_bounds__(64) k_cross_attn2(
    const float* __restrict__ qkv_c,
    float* __restrict__ l_c, float* __restrict__ acc_c) {
  int bid = blockIdx.x;            // grid 2048 = 4b * 8h * 16qt * 4ks
  int ks = bid & 3, qt = (bid >> 2) & 15, h = (bid >> 6) & 7, b = bid >> 9;
  const float* base = qkv_c + (size_t)b*TT*192;
  int q = qt*64 + threadIdx.x;
  float qv[8];
  #pragma unroll
  for (int c = 0; c < 8; ++c) qv[c] = base[q*192 + h*8 + c] * 0.35355339f; // 1/sqrt(8)
  float l = 0.f, acc[8];
  #pragma unroll
  for (int c = 0; c < 8; ++c) acc[c] = 0.f;
  int k0 = ks*256;
  #pragma unroll 2
  for (int k = k0; k < k0 + 256; ++k) {
    const float* kr = base + (size_t)k*192 + 64  + h*8;  // K: channels 64+h*8..71+h*8
    const float* vr = base + (size_t)k*192 + 128 + h*8;  // V: channels 128+h*8..135+h*8
    float s = 0.f;
    #pragma unroll
    for (int c = 0; c < 8; ++c) s += qv[c] * kr[c];
    float p = __expf(s);
    l += p;
    #pragma unroll
    for (int c = 0; c < 8; ++c) acc[c] += p * vr[c];
  }
  int base_o = (b*8 + h)*TT + q;
  atomicAdd(l_c + base_o, l);
  #pragma unroll
  for (int c = 0; c < 8; ++c) atomicAdd(acc_c + base_o*8 + c, acc[c]);
}

// ---------- K5: normalize PV, Wo_c projection, residual, LN1 ----------
__global__ void __launch_bounds__(256) k_finalize_cross(
    const float* __restrict__ all_blocks,
    const float* __restrict__ l_c, const float* __restrict__ acc_c,
    const void* __restrict__ Wo_c, const void* __restrict__ bo_c,
    const void* __restrict__ g1, const void* __restrict__ be1,
    const int* __restrict__ flags,
    float* __restrict__ ln1) {
  __shared__ float pvs[4*64];
  bool isbf = flags[0];
  int tt = threadIdx.x >> 6, j = threadIdx.x & 63;  // one token per wave, lane = channel
  int t = blockIdx.x*4 + tt;       // grid 1024
  int b = t >> 10, tl = t & 1023;
  int h = j >> 3;
  int idx = (b*8 + h)*TT + tl;
  pvs[tt*64 + j] = acc_c[idx*8 + (j & 7)] * rcpf(l_c[idx]);
  __syncthreads();
  float a = ldf(bo_c, j, isbf);
  const float* p = pvs + tt*64;
  #pragma unroll
  for (int m = 0; m < 64; m += 8) a += dot8_any(Wo_c, j*64 + m, p + m, isbf);
  float x = all_blocks[t*64 + j] + a;
  float s = x, s2 = x*x;
  #pragma unroll
  for (int off = 32; off; off >>= 1) { s += __shfl_xor(s, off); s2 += __shfl_xor(s2, off); }
  float mu  = s  * (1.f/64.f);
  float var = s2 * (1.f/64.f) - mu*mu;
  float y = (x - mu) * rsqrtf(var + 1e-5f) * ldf(g1, j, isbf) + ldf(be1, j, isbf);
  ln1[t*64 + j] = y;
}

// ---------- K6: recv transposed — thread owns 4 keys, loop queries (s_load), no atomics ----------
__global__ void __launch_bounds__(64) k_recv_t(
    const float* __restrict__ qkv_c,
    const float* __restrict__ l_c,
    float* __restrict__ recv_part) {
  int bid = blockIdx.x;            // grid 2048 = 4b * 8h * 4kt * 16qs
  int qs = bid & 15, kt = (bid >> 4) & 3, h = (bid >> 6) & 7, b = bid >> 9;
  const float* base = qkv_c + (size_t)b*TT*192;
  const float* lrow = l_c + (b*8 + h)*TT;
  float kv[4][8];
  #pragma unroll
  for (int i = 0; i < 4; ++i) {
    int k = kt*256 + i*64 + threadIdx.x;
    #pragma unroll
    for (int c = 0; c < 8; ++c)
      kv[i][c] = base[(size_t)k*192 + 64 + h*8 + c] * 0.35355339f;
  }
  float acc[4] = {0.f, 0.f, 0.f, 0.f};
  #pragma unroll 2
  for (int qq = 0; qq < 64; ++qq) {
    int q = qs*64 + qq;
    const float* qr = base + (size_t)q*192 + h*8;   // uniform -> SMEM
    float q0=qr[0],q1=qr[1],q2=qr[2],q3=qr[3],q4=qr[4],q5=qr[5],q6=qr[6],q7=qr[7];
    float invl = rcpf(lrow[q]);                     // uniform load + rcp
    #pragma unroll
    for (int i = 0; i < 4; ++i) {
      float s = q0*kv[i][0] + q1*kv[i][1] + q2*kv[i][2] + q3*kv[i][3]
              + q4*kv[i][4] + q5*kv[i][5] + q6*kv[i][6] + q7*kv[i][7];
      acc[i] += __expf(s) * invl;
    }
  }
  int src = h*16 + qs;             // 128 sources
  #pragma unroll
  for (int i = 0; i < 4; ++i) {
    int k = kt*256 + i*64 + threadIdx.x;
    recv_part[((size_t)(b*1024 + k))*128 + src] = acc[i];
  }
}

// ---------- K6b: reduce 128 partials -> attn_recv ----------
__global__ void __launch_bounds__(256) k_recv_reduce(
    const float* __restrict__ recv_part, float* __restrict__ attn_recv) {
  int g = blockIdx.x * 256 + threadIdx.x;   // 4096 = b*1024+k
  const float4* p = (const float4*)(recv_part + (size_t)g*128);
  float s = 0.f;
  #pragma unroll
  for (int i = 0; i < 32; ++i) {
    float4 v = p[i];
    s += v.x + v.y + v.z + v.w;
  }
  attn_recv[g] = s * (1.f/8192.f);          // /(H=8 * T=1024)
}

// ---------- K7: FFN + LN2 + sensitivity gate + un-blocking to 8x8 ----------
__global__ void __launch_bounds__(256) k_ffn_out(
    const float* __restrict__ ln1,
    const void* __restrict__ W1b, const void* __restrict__ b1b,
    const void* __restrict__ W2b, const void* __restrict__ b2b,
    const void* __restrict__ g2, const void* __restrict__ be2,
    const float* __restrict__ blocks,
    const int* __restrict__ tok32,
    const float* __restrict__ attn_recv,
    const void* __restrict__ sens_emb,
    const void* __restrict__ sens_alpha,
    const int* __restrict__ flags,
    void* __restrict__ out) {
  __shared__ float ld[4*64];
  __shared__ float hbuf[4*256];
  bool isbf = flags[0];
  int t0 = blockIdx.x * 4;         // grid 1024, 4 tokens per WG
  ld[threadIdx.x] = ln1[t0*64 + threadIdx.x];
  __syncthreads();
  {
    float acc[4];
    float bb = ldf(b1b, threadIdx.x, isbf);
    #pragma unroll
    for (int tt = 0; tt < 4; ++tt) acc[tt] = bb;
    #pragma unroll
    for (int j = 0; j < 64; j += 8) {
      float w[8]; load8_any(W1b, threadIdx.x*64 + j, w, isbf);
      #pragma unroll
      for (int jj = 0; jj < 8; ++jj)
        #pragma unroll
        for (int tt = 0; tt < 4; ++tt) acc[tt] += w[jj] * ld[tt*64 + j + jj];
    }
    #pragma unroll
    for (int tt = 0; tt < 4; ++tt) {
      float v = acc[tt];
      hbuf[tt*256 + threadIdx.x] = 0.5f * v * (1.f + erff(v * 0.70710678f));
    }
  }
  __syncthreads();
  int tt = threadIdx.x >> 6, j = threadIdx.x & 63;   // token per wave, lane = channel
  int t = t0 + tt, b = t >> 10, tl = t & 1023;
  float y = ldf(b2b, j, isbf);
  const float* hb = hbuf + tt*256;
  #pragma unroll
  for (int k = 0; k < 256; k += 8) y += dot8_any(W2b, j*256 + k, hb + k, isbf);
  float z = ld[tt*64 + j] + y;
  float s = z, s2 = z*z;
  #pragma unroll
  for (int off = 32; off; off >>= 1) { s += __shfl_xor(s, off); s2 += __shfl_xor(s2, off); }
  float mu  = s  * (1.f/64.f);
  float var = s2 * (1.f/64.f) - mu*mu;
  float y2 = (z - mu) * rsqrtf(var + 1e-5f) * ldf(g2, j, isbf) + ldf(be2, j, isbf);
  int tok = flags[1] ? tok32[t*2] : tok32[t];
  int i = j >> 2, e = j & 3;
  float recv = attn_recv[b*TT + tl];
  float sv = ldf(sens_emb, tok*16 + i, isbf) + recv * ldf(sens_alpha, i, isbf);
  float sg = rcpf(1.f + __expf(-sv));
  float blk = blocks[t*64 + j];
  float nb = blk + (y2 - blk) * sg;
  int rb = i >> 2, cb = i & 3, r = e >> 1, c = e & 1;
  int oidx = t*64 + (rb*2 + r)*8 + cb*2 + c;
  if (isbf) ((__hip_bfloat16*)out)[oidx] = __float2bfloat16(nb);
  else      ((float*)out)[oidx] = nb;
}

extern "C" void kernel_launch(void* const* d_in, const int* in_sizes, int n_in,
                              void* d_out, int out_size, void* d_ws, size_t ws_size,
                              hipStream_t stream) {
  const void* M        = d_in[0];
  const int*  tok      = (const int*)d_in[1];
  const void* Wqkv_blk = d_in[2];
  const void* bqkv_blk = d_in[3];
  const void* Wo_blk   = d_in[4];
  const void* bo_blk   = d_in[5];
  const void* Wqkv_c   = d_in[6];
  const void* bqkv_c   = d_in[7];
  const void* Wo_c     = d_in[8];
  const void* bo_c     = d_in[9];
  const void* W1       = d_in[10];
  const void* b1       = d_in[11];
  const void* W2       = d_in[12];
  const void* b2       = d_in[13];
  const void* g1       = d_in[14];
  const void* be1      = d_in[15];
  const void* g2i      = d_in[16];
  const void* be2      = d_in[17];
  const void* sens_emb = d_in[18];
  const void* sens_al  = d_in[19];

  float* ws = (float*)d_ws;
  float* blocks    = ws + OFF_BLOCKS;
  float* qkv_blk   = ws + OFF_QKVB;
  float* recv_part = ws + OFF_RECVP;   // aliases qkv_blk (dead by then)
  float* all_blk   = ws + OFF_ALLB;
  float* qkv_c     = ws + OFF_QKVC;
  float* l_c       = ws + OFF_LC;
  float* acc_c     = ws + OFF_ACCC;
  float* attn_recv = ws + OFF_RECV;
  float* ln1       = ws + OFF_LN1;
  int*   flags     = (int*)(ws + OFF_FLAGS);

  // zero the atomic accumulators (l_c, acc_c contiguous)
  hipMemsetAsync(l_c, 0, (size_t)(32768 + 262144) * sizeof(float), stream);

  k_detect<<<1, 64, 0, stream>>>(M, tok, flags);
  k_prep<<<256, 256, 0, stream>>>(M, Wqkv_blk, bqkv_blk, flags, blocks, qkv_blk);
  k_blk_attn2<<<1024, 64, 0, stream>>>(qkv_blk, Wo_blk, bo_blk, flags, all_blk);
  k_qkv_c<<<512, 256, 0, stream>>>(all_blk, Wqkv_c, bqkv_c, flags, qkv_c);
  k_cross_attn2<<<2048, 64, 0, stream>>>(qkv_c, l_c, acc_c);
  k_finalize_cross<<<1024, 256, 0, stream>>>(all_blk, l_c, acc_c, Wo_c, bo_c, g1, be1, flags, ln1);
  k_recv_t<<<2048, 64, 0, stream>>>(qkv_c, l_c, recv_part);
  k_recv_reduce<<<16, 256, 0, stream>>>(recv_part, attn_recv);
  k_ffn_out<<<1024, 256, 0, stream>>>(ln1, W1, b1, W2, b2, g2i, be2,
                                      blocks, tok, attn_recv, sens_emb, sens_al,
                                      flags, (void*)d_out);
}

// Round 5
// 330.771 us; speedup vs baseline: 1.5932x; 1.2189x over previous
//
#include <hip/hip_runtime.h>
#include <hip/hip_bf16.h>
#include <math.h>

// Problem constants (setup_inputs: B=4, T=1024)
#define BB 4
#define TT 1024
#define BT 4096

// Workspace layout (fp32 offsets in floats)
#define OFF_BLOCKS 0          // [BT][64]  blocks in [i*4+e] channel order
#define OFF_QKVB   262144     // [16][BT][12] per-block qkv (dead after k_blk_part)
#define OFF_RECVP  262144     // [B][1024k][128src] recv partials (aliases QKVB)
#define OFF_ALLB   1048576    // [BT][64]  per-block MHA output (all_blocks)
#define OFF_QKVC   1310720    // [BT][192] cross qkv
#define OFF_LC     2097152    // [B*8][T]  cross softmax denominators (unnormalized)
#define OFF_ACCC   2129920    // [B*8][T][8] cross PV (normalized by l)
#define OFF_RECV   2392064    // [B][T]    attention-received column means
#define OFF_LN1    2396160    // [BT][64]  post-LN1 activations
#define OFF_FLAGS  2658304    // [16] ints: [0]=floats-are-bf16, [1]=tokens-are-int64
#define WS_FLOATS  2658320

__device__ inline float rcpf(float x) { return __builtin_amdgcn_rcpf(x); }

// ---------- dtype-flexible load helpers ----------
__device__ inline float ldf(const void* p, int i, bool isbf) {
  return isbf ? __bfloat162float(((const __hip_bfloat16*)p)[i])
              : ((const float*)p)[i];
}

__device__ inline void bf16x8_to_f32(const __hip_bfloat16* p, float* w) {
  uint4 u = *reinterpret_cast<const uint4*>(p);
  w[0] = __uint_as_float(u.x << 16); w[1] = __uint_as_float(u.x & 0xffff0000u);
  w[2] = __uint_as_float(u.y << 16); w[3] = __uint_as_float(u.y & 0xffff0000u);
  w[4] = __uint_as_float(u.z << 16); w[5] = __uint_as_float(u.z & 0xffff0000u);
  w[6] = __uint_as_float(u.w << 16); w[7] = __uint_as_float(u.w & 0xffff0000u);
}

__device__ inline void load8_any(const void* p, int off, float* w, bool isbf) {
  if (isbf) {
    bf16x8_to_f32((const __hip_bfloat16*)p + off, w);
  } else {
    const float4* f = (const float4*)((const float*)p + off);
    float4 a = f[0], b = f[1];
    w[0]=a.x; w[1]=a.y; w[2]=a.z; w[3]=a.w; w[4]=b.x; w[5]=b.y; w[6]=b.z; w[7]=b.w;
  }
}

__device__ inline float dot8_any(const void* W, int off, const float* x, bool isbf) {
  float w[8]; load8_any(W, off, w, isbf);
  return w[0]*x[0] + w[1]*x[1] + w[2]*x[2] + w[3]*x[3]
       + w[4]*x[4] + w[5]*x[5] + w[6]*x[6] + w[7]*x[7];
}

// ---------- K0: dtype detection ----------
__global__ void __launch_bounds__(64) k_detect(
    const void* __restrict__ M, const int* __restrict__ tok, int* __restrict__ flags) {
  const unsigned short* h = (const unsigned short*)M;
  unsigned short v = h[threadIdx.x];
  int e = (v >> 7) & 0xff;
  bool pass = (e >= 90) && (e <= 141);
  unsigned long long m = __ballot(pass);
  if (threadIdx.x == 0) {
    flags[0] = (__popcll(m) >= 58) ? 1 : 0;
    flags[1] = ((tok[1] | tok[3] | tok[5] | tok[7]) == 0) ? 1 : 0;
  }
}

// ---------- K1: blocks gather + per-block QKV ----------
__global__ void __launch_bounds__(256) k_prep(
    const void* __restrict__ M,
    const void* __restrict__ Wqkv_blk,
    const void* __restrict__ bqkv_blk,
    const int* __restrict__ flags,
    float* __restrict__ blocks, float* __restrict__ qkv_blk) {
  bool isbf = flags[0];
  int g = blockIdx.x * 256 + threadIdx.x;        // 65536 = 16 blocks * 4096 tokens
  int i = g >> 12, bt = g & 4095;
  int rb = i >> 2, cb = i & 3;
  float x[4];
  #pragma unroll
  for (int r = 0; r < 2; ++r)
    #pragma unroll
    for (int c = 0; c < 2; ++c)
      x[r*2+c] = ldf(M, bt*64 + (rb*2+r)*8 + cb*2 + c, isbf);
  float* bo = blocks + bt*64 + i*4;
  #pragma unroll
  for (int j = 0; j < 4; ++j) bo[j] = x[j];
  float* o = qkv_blk + (i*BT + bt) * 12;
  #pragma unroll
  for (int c = 0; c < 12; ++c) {
    float a = ldf(bqkv_blk, i*12 + c, isbf);
    #pragma unroll
    for (int j = 0; j < 4; ++j) a += ldf(Wqkv_blk, i*48 + c*4 + j, isbf) * x[j];
    o[c] = a;
  }
}

// ---------- K2: per-block attention, 8 waves key-split in-block, LDS merge ----------
__global__ void __launch_bounds__(512) k_blk_part(
    const float* __restrict__ qkv_blk,
    const void* __restrict__ Wo_blk,
    const void* __restrict__ bo_blk,
    const int* __restrict__ flags,
    float* __restrict__ all_blocks) {
  __shared__ float red[64*49];       // [ql][wv*6+c], stride 49 (odd -> conflict-free)
  int bid = blockIdx.x;              // grid 1024 = 16i * 4b * 16qt
  int qt = bid & 15, b = (bid >> 4) & 3, i = bid >> 6;
  int tid = threadIdx.x;
  int wv = __builtin_amdgcn_readfirstlane(tid) >> 6;   // wave id 0..7 in SGPR
  int ql = tid & 63;
  const float* base = qkv_blk + (size_t)(i*BT + b*TT) * 12;
  int q = qt*64 + ql;
  const float* qr = base + q*12;
  const float S2 = 0.70710678f;      // 1/sqrt(Dh=2)
  float q00 = qr[0]*S2, q01 = qr[1]*S2;   // head 0
  float q10 = qr[2]*S2, q11 = qr[3]*S2;   // head 1
  float l0=0.f, l1=0.f, a00=0.f, a01=0.f, a10=0.f, a11=0.f;
  int kbeg = wv*128;
  #pragma unroll 4
  for (int k = kbeg; k < kbeg + 128; ++k) {
    const float* kr = base + k*12 + 4;    // uniform address -> s_load_dwordx8
    float k0=kr[0], k1=kr[1], k2=kr[2], k3=kr[3];
    float v0=kr[4], v1=kr[5], v2=kr[6], v3=kr[7];
    float p0 = __expf(q00*k0 + q01*k1);
    float p1 = __expf(q10*k2 + q11*k3);
    l0 += p0; a00 += p0*v0; a01 += p0*v1;
    l1 += p1; a10 += p1*v2; a11 += p1*v3;
  }
  float* rr = red + ql*49 + wv*6;
  rr[0]=l0; rr[1]=l1; rr[2]=a00; rr[3]=a01; rr[4]=a10; rr[5]=a11;
  __syncthreads();
  if (tid < 64) {
    bool isbf = flags[0];
    float s[6] = {0.f,0.f,0.f,0.f,0.f,0.f};
    #pragma unroll
    for (int w = 0; w < 8; ++w) {
      const float* p = red + tid*49 + w*6;
      #pragma unroll
      for (int c = 0; c < 6; ++c) s[c] += p[c];
    }
    float r0 = rcpf(s[0]), r1 = rcpf(s[1]);
    float o[4] = { s[2]*r0, s[3]*r0, s[4]*r1, s[5]*r1 };
    int q2 = qt*64 + tid;
    float* outp = all_blocks + (size_t)(b*TT + q2)*64 + i*4;
    #pragma unroll
    for (int j = 0; j < 4; ++j) {
      float a = ldf(bo_blk, i*4 + j, isbf);
      #pragma unroll
      for (int m2 = 0; m2 < 4; ++m2) a += ldf(Wo_blk, i*16 + j*4 + m2, isbf) * o[m2];
      outp[j] = a;
    }
  }
}

// ---------- K3: cross QKV projection (64 -> 192) ----------
__global__ void __launch_bounds__(256) k_qkv_c(
    const float* __restrict__ all_blocks,
    const void* __restrict__ Wqkv_c,
    const void* __restrict__ bqkv_c,
    const int* __restrict__ flags,
    float* __restrict__ qkv_c) {
  __shared__ float xs[8*64];
  bool isbf = flags[0];
  int t0 = blockIdx.x * 8;         // grid 512
  for (int idx = threadIdx.x; idx < 512; idx += 256)
    xs[idx] = all_blocks[t0*64 + idx];
  __syncthreads();
  int tok = threadIdx.x >> 5, lane32 = threadIdx.x & 31;
  const float* x = xs + tok*64;
  #pragma unroll
  for (int kk = 0; kk < 6; ++kk) {
    int c = kk*32 + lane32;
    float a = ldf(bqkv_c, c, isbf);
    #pragma unroll
    for (int j = 0; j < 64; j += 8) a += dot8_any(Wqkv_c, c*64 + j, x + j, isbf);
    qkv_c[(t0 + tok)*192 + c] = a;
  }
}

// ---------- K4: cross attention, 8 waves key-split in-block, LDS merge, no atomics ----------
__global__ void __launch_bounds__(512) k_cross3(
    const float* __restrict__ qkv_c,
    float* __restrict__ l_c, float* __restrict__ acc_c) {
  __shared__ float red[64*73];       // [ql][wv*9+c], stride 73 (odd -> conflict-free)
  int bid = blockIdx.x;              // grid 512 = 4b * 8h * 16qt
  int qt = bid & 15, h = (bid >> 4) & 7, b = bid >> 7;
  int tid = threadIdx.x;
  int wv = __builtin_amdgcn_readfirstlane(tid) >> 6;
  int ql = tid & 63;
  const float* base = qkv_c + (size_t)b*TT*192;
  int q = qt*64 + ql;
  float qv[8];
  #pragma unroll
  for (int c = 0; c < 8; ++c) qv[c] = base[q*192 + h*8 + c] * 0.35355339f; // 1/sqrt(8)
  float l = 0.f, acc[8];
  #pragma unroll
  for (int c = 0; c < 8; ++c) acc[c] = 0.f;
  int kbeg = wv*128;
  #pragma unroll 2
  for (int k = kbeg; k < kbeg + 128; ++k) {
    const float* kr = base + (size_t)k*192 + 64  + h*8;  // K chans: uniform -> s_load
    const float* vr = base + (size_t)k*192 + 128 + h*8;  // V chans: uniform -> s_load
    float s = 0.f;
    #pragma unroll
    for (int c = 0; c < 8; ++c) s += qv[c] * kr[c];
    float p = __expf(s);
    l += p;
    #pragma unroll
    for (int c = 0; c < 8; ++c) acc[c] += p * vr[c];
  }
  float* rr = red + ql*73 + wv*9;
  rr[0] = l;
  #pragma unroll
  for (int c = 0; c < 8; ++c) rr[1+c] = acc[c];
  __syncthreads();
  if (tid < 64) {
    float ls = 0.f, as[8];
    #pragma unroll
    for (int c = 0; c < 8; ++c) as[c] = 0.f;
    #pragma unroll
    for (int w = 0; w < 8; ++w) {
      const float* p = red + tid*73 + w*9;
      ls += p[0];
      #pragma unroll
      for (int c = 0; c < 8; ++c) as[c] += p[1+c];
    }
    float invl = rcpf(ls);
    int q2 = qt*64 + tid;
    int idx = (b*8 + h)*TT + q2;
    l_c[idx] = ls;
    #pragma unroll
    for (int c = 0; c < 8; ++c) acc_c[idx*8 + c] = as[c] * invl;   // normalized PV
  }
}

// ---------- K5: Wo_c projection on normalized PV, residual, LN1 ----------
__global__ void __launch_bounds__(256) k_finalize_cross(
    const float* __restrict__ all_blocks,
    const float* __restrict__ acc_c,
    const void* __restrict__ Wo_c, const void* __restrict__ bo_c,
    const void* __restrict__ g1, const void* __restrict__ be1,
    const int* __restrict__ flags,
    float* __restrict__ ln1) {
  __shared__ float pvs[4*64];
  bool isbf = flags[0];
  int tt = threadIdx.x >> 6, j = threadIdx.x & 63;  // one token per wave, lane = channel
  int t = blockIdx.x*4 + tt;       // grid 1024
  int b = t >> 10, tl = t & 1023;
  int h = j >> 3;
  int idx = (b*8 + h)*TT + tl;
  pvs[tt*64 + j] = acc_c[idx*8 + (j & 7)];
  __syncthreads();
  float a = ldf(bo_c, j, isbf);
  const float* p = pvs + tt*64;
  #pragma unroll
  for (int m = 0; m < 64; m += 8) a += dot8_any(Wo_c, j*64 + m, p + m, isbf);
  float x = all_blocks[t*64 + j] + a;
  float s = x, s2 = x*x;
  #pragma unroll
  for (int off = 32; off; off >>= 1) { s += __shfl_xor(s, off); s2 += __shfl_xor(s2, off); }
  float mu  = s  * (1.f/64.f);
  float var = s2 * (1.f/64.f) - mu*mu;
  float y = (x - mu) * rsqrtf(var + 1e-5f) * ldf(g1, j, isbf) + ldf(be1, j, isbf);
  ln1[t*64 + j] = y;
}

// ---------- K6: recv transposed — thread owns 4 keys, 32-query slices, 2-way atomic ----------
__global__ void __launch_bounds__(64) k_recv_t2(
    const float* __restrict__ qkv_c,
    const float* __restrict__ l_c,
    float* __restrict__ recv_part) {
  int bid = blockIdx.x;              // grid 4096 = 4b * 8h * 4kt * 32qs
  int qs = bid & 31, kt = (bid >> 5) & 3, h = (bid >> 7) & 7, b = bid >> 10;
  const float* base = qkv_c + (size_t)b*TT*192;
  const float* lrow = l_c + (b*8 + h)*TT;
  float kv[4][8];
  #pragma unroll
  for (int i = 0; i < 4; ++i) {
    int k = kt*256 + i*64 + threadIdx.x;
    #pragma unroll
    for (int c = 0; c < 8; ++c)
      kv[i][c] = base[(size_t)k*192 + 64 + h*8 + c] * 0.35355339f;
  }
  float acc[4] = {0.f, 0.f, 0.f, 0.f};
  #pragma unroll 2
  for (int qq = 0; qq < 32; ++qq) {
    int q = qs*32 + qq;
    const float* qr = base + (size_t)q*192 + h*8;   // uniform -> s_load
    float q0=qr[0],q1=qr[1],q2=qr[2],q3=qr[3],q4=qr[4],q5=qr[5],q6=qr[6],q7=qr[7];
    float invl = rcpf(lrow[q]);                     // uniform load + rcp
    #pragma unroll
    for (int i = 0; i < 4; ++i) {
      float s = q0*kv[i][0] + q1*kv[i][1] + q2*kv[i][2] + q3*kv[i][3]
              + q4*kv[i][4] + q5*kv[i][5] + q6*kv[i][6] + q7*kv[i][7];
      acc[i] += __expf(s) * invl;
    }
  }
  int src = h*16 + (qs >> 1);        // 128 sources; 2 contributors each (commutative)
  #pragma unroll
  for (int i = 0; i < 4; ++i) {
    int k = kt*256 + i*64 + threadIdx.x;
    atomicAdd(recv_part + ((size_t)(b*1024 + k))*128 + src, acc[i]);
  }
}

// ---------- K6b: reduce 128 partials -> attn_recv ----------
__global__ void __launch_bounds__(256) k_recv_reduce(
    const float* __restrict__ recv_part, float* __restrict__ attn_recv) {
  int g = blockIdx.x * 256 + threadIdx.x;   // 4096 = b*1024+k
  const float4* p = (const float4*)(recv_part + (size_t)g*128);
  float s = 0.f;
  #pragma unroll
  for (int i = 0; i < 32; ++i) {
    float4 v = p[i];
    s += v.x + v.y + v.z + v.w;
  }
  attn_recv[g] = s * (1.f/8192.f);          // /(H=8 * T=1024)
}

// ---------- K7: FFN + LN2 + sensitivity gate + un-blocking to 8x8 ----------
__global__ void __launch_bounds__(256) k_ffn_out(
    const float* __restrict__ ln1,
    const void* __restrict__ W1b, const void* __restrict__ b1b,
    const void* __restrict__ W2b, const void* __restrict__ b2b,
    const void* __restrict__ g2, const void* __restrict__ be2,
    const float* __restrict__ blocks,
    const int* __restrict__ tok32,
    const float* __restrict__ attn_recv,
    const void* __restrict__ sens_emb,
    const void* __restrict__ sens_alpha,
    const int* __restrict__ flags,
    void* __restrict__ out) {
  __shared__ float ld[4*64];
  __shared__ float hbuf[4*256];
  bool isbf = flags[0];
  int t0 = blockIdx.x * 4;         // grid 1024, 4 tokens per WG
  ld[threadIdx.x] = ln1[t0*64 + threadIdx.x];
  __syncthreads();
  {
    float acc[4];
    float bb = ldf(b1b, threadIdx.x, isbf);
    #pragma unroll
    for (int tt = 0; tt < 4; ++tt) acc[tt] = bb;
    #pragma unroll
    for (int j = 0; j < 64; j += 8) {
      float w[8]; load8_any(W1b, threadIdx.x*64 + j, w, isbf);
      #pragma unroll
      for (int jj = 0; jj < 8; ++jj)
        #pragma unroll
        for (int tt = 0; tt < 4; ++tt) acc[tt] += w[jj] * ld[tt*64 + j + jj];
    }
    #pragma unroll
    for (int tt = 0; tt < 4; ++tt) {
      float v = acc[tt];
      // tanh-GELU in sigmoid form: v * sigmoid(1.5957691*v + 0.07135481*v^3)
      float u = 1.5957691f*v + 0.07135481f*v*v*v;
      hbuf[tt*256 + threadIdx.x] = v * rcpf(1.f + __expf(-u));
    }
  }
  __syncthreads();
  int tt = threadIdx.x >> 6, j = threadIdx.x & 63;   // token per wave, lane = channel
  int t = t0 + tt, b = t >> 10, tl = t & 1023;
  float y = ldf(b2b, j, isbf);
  const float* hb = hbuf + tt*256;
  #pragma unroll
  for (int k = 0; k < 256; k += 8) y += dot8_any(W2b, j*256 + k, hb + k, isbf);
  float z = ld[tt*64 + j] + y;
  float s = z, s2 = z*z;
  #pragma unroll
  for (int off = 32; off; off >>= 1) { s += __shfl_xor(s, off); s2 += __shfl_xor(s2, off); }
  float mu  = s  * (1.f/64.f);
  float var = s2 * (1.f/64.f) - mu*mu;
  float y2 = (z - mu) * rsqrtf(var + 1e-5f) * ldf(g2, j, isbf) + ldf(be2, j, isbf);
  int tok = flags[1] ? tok32[t*2] : tok32[t];
  int i = j >> 2, e = j & 3;
  float recv = attn_recv[b*TT + tl];
  float sv = ldf(sens_emb, tok*16 + i, isbf) + recv * ldf(sens_alpha, i, isbf);
  float sg = rcpf(1.f + __expf(-sv));
  float blk = blocks[t*64 + j];
  float nb = blk + (y2 - blk) * sg;
  int rb = i >> 2, cb = i & 3, r = e >> 1, c = e & 1;
  int oidx = t*64 + (rb*2 + r)*8 + cb*2 + c;
  if (isbf) ((__hip_bfloat16*)out)[oidx] = __float2bfloat16(nb);
  else      ((float*)out)[oidx] = nb;
}

extern "C" void kernel_launch(void* const* d_in, const int* in_sizes, int n_in,
                              void* d_out, int out_size, void* d_ws, size_t ws_size,
                              hipStream_t stream) {
  const void* M        = d_in[0];
  const int*  tok      = (const int*)d_in[1];
  const void* Wqkv_blk = d_in[2];
  const void* bqkv_blk = d_in[3];
  const void* Wo_blk   = d_in[4];
  const void* bo_blk   = d_in[5];
  const void* Wqkv_c   = d_in[6];
  const void* bqkv_c   = d_in[7];
  const void* Wo_c     = d_in[8];
  const void* bo_c     = d_in[9];
  const void* W1       = d_in[10];
  const void* b1       = d_in[11];
  const void* W2       = d_in[12];
  const void* b2       = d_in[13];
  const void* g1       = d_in[14];
  const void* be1      = d_in[15];
  const void* g2i      = d_in[16];
  const void* be2      = d_in[17];
  const void* sens_emb = d_in[18];
  const void* sens_al  = d_in[19];

  float* ws = (float*)d_ws;
  float* blocks    = ws + OFF_BLOCKS;
  float* qkv_blk   = ws + OFF_QKVB;
  float* recv_part = ws + OFF_RECVP;   // aliases qkv_blk (dead after k_blk_part)
  float* all_blk   = ws + OFF_ALLB;
  float* qkv_c     = ws + OFF_QKVC;
  float* l_c       = ws + OFF_LC;
  float* acc_c     = ws + OFF_ACCC;
  float* attn_recv = ws + OFF_RECV;
  float* ln1       = ws + OFF_LN1;
  int*   flags     = (int*)(ws + OFF_FLAGS);

  k_detect<<<1, 64, 0, stream>>>(M, tok, flags);
  k_prep<<<256, 256, 0, stream>>>(M, Wqkv_blk, bqkv_blk, flags, blocks, qkv_blk);
  k_blk_part<<<1024, 512, 0, stream>>>(qkv_blk, Wo_blk, bo_blk, flags, all_blk);
  // qkv_blk now dead; zero the recv partial accumulator that aliases it
  hipMemsetAsync(recv_part, 0, (size_t)(4*1024*128) * sizeof(float), stream);
  k_qkv_c<<<512, 256, 0, stream>>>(all_blk, Wqkv_c, bqkv_c, flags, qkv_c);
  k_cross3<<<512, 512, 0, stream>>>(qkv_c, l_c, acc_c);
  k_finalize_cross<<<1024, 256, 0, stream>>>(all_blk, acc_c, Wo_c, bo_c, g1, be1, flags, ln1);
  k_recv_t2<<<4096, 64, 0, stream>>>(qkv_c, l_c, recv_part);
  k_recv_reduce<<<16, 256, 0, stream>>>(recv_part, attn_recv);
  k_ffn_out<<<1024, 256, 0, stream>>>(ln1, W1, b1, W2, b2, g2i, be2,
                                      blocks, tok, attn_recv, sens_emb, sens_al,
                                      flags, (void*)d_out);
}

// Round 6
// 310.490 us; speedup vs baseline: 1.6973x; 1.0653x over previous
//
#include <hip/hip_runtime.h>
#include <hip/hip_bf16.h>
#include <math.h>

// Problem constants (setup_inputs: B=4, T=1024)
#define BB 4
#define TT 1024
#define BT 4096

// Workspace layout (fp32 offsets in floats)
#define OFF_BLOCKS 0          // [BT][64]  blocks in [i*4+e] channel order
#define OFF_QKVB   262144     // [16][BT][12] per-block qkv (dead after k_blk_part)
#define OFF_RECVP  262144     // [B][1024k][128src] recv partials (aliases QKVB)
#define OFF_ALLB   1048576    // [BT][64]  per-block MHA output (all_blocks)
#define OFF_QKVC   1310720    // [BT][192] cross qkv
#define OFF_LC     2097152    // [B*8][T]  cross softmax denominators (unnormalized)
#define OFF_ACCC   2129920    // [B*8][T][8] cross PV (normalized by l)
#define OFF_RECV   2392064    // [B][T]    attention-received column means
#define OFF_LN1    2396160    // [BT][64]  post-LN1 activations
#define OFF_FLAGS  2658304    // [16] ints: [0]=floats-are-bf16, [1]=tokens-are-int64
#define WS_FLOATS  2658320

__device__ inline float rcpf(float x) { return __builtin_amdgcn_rcpf(x); }

// ---------- dtype-templated load helpers (single path per instantiation) ----------
template <bool ISBF>
__device__ inline float ldf(const void* p, int i) {
  if (ISBF) return __bfloat162float(((const __hip_bfloat16*)p)[i]);
  else      return ((const float*)p)[i];
}

template <bool ISBF>
__device__ inline void load8(const void* p, int off, float* w) {
  if (ISBF) {
    uint4 u = *reinterpret_cast<const uint4*>((const __hip_bfloat16*)p + off);
    w[0] = __uint_as_float(u.x << 16); w[1] = __uint_as_float(u.x & 0xffff0000u);
    w[2] = __uint_as_float(u.y << 16); w[3] = __uint_as_float(u.y & 0xffff0000u);
    w[4] = __uint_as_float(u.z << 16); w[5] = __uint_as_float(u.z & 0xffff0000u);
    w[6] = __uint_as_float(u.w << 16); w[7] = __uint_as_float(u.w & 0xffff0000u);
  } else {
    const float4* f = (const float4*)((const float*)p + off);
    float4 a = f[0], b = f[1];
    w[0]=a.x; w[1]=a.y; w[2]=a.z; w[3]=a.w; w[4]=b.x; w[5]=b.y; w[6]=b.z; w[7]=b.w;
  }
}

template <bool ISBF>
__device__ inline float dot8(const void* W, int off, const float* x) {
  float w[8]; load8<ISBF>(W, off, w);
  return w[0]*x[0] + w[1]*x[1] + w[2]*x[2] + w[3]*x[3]
       + w[4]*x[4] + w[5]*x[5] + w[6]*x[6] + w[7]*x[7];
}

// ---------- K0: dtype detection ----------
__global__ void __launch_bounds__(64) k_detect(
    const void* __restrict__ M, const int* __restrict__ tok, int* __restrict__ flags) {
  const unsigned short* h = (const unsigned short*)M;
  unsigned short v = h[threadIdx.x];
  int e = (v >> 7) & 0xff;
  bool pass = (e >= 90) && (e <= 141);
  unsigned long long m = __ballot(pass);
  if (threadIdx.x == 0) {
    flags[0] = (__popcll(m) >= 58) ? 1 : 0;
    flags[1] = ((tok[1] | tok[3] | tok[5] | tok[7]) == 0) ? 1 : 0;
  }
}

// ---------- K1: blocks gather + per-block QKV ----------
template <bool ISBF>
__global__ void __launch_bounds__(256) k_prep(
    const void* __restrict__ M,
    const void* __restrict__ Wqkv_blk,
    const void* __restrict__ bqkv_blk,
    const int* __restrict__ flags,
    float* __restrict__ blocks, float* __restrict__ qkv_blk) {
  if ((bool)flags[0] != ISBF) return;
  int g = blockIdx.x * 256 + threadIdx.x;        // 65536 = 16 blocks * 4096 tokens
  int i = g >> 12, bt = g & 4095;
  int rb = i >> 2, cb = i & 3;
  float x[4];
  #pragma unroll
  for (int r = 0; r < 2; ++r)
    #pragma unroll
    for (int c = 0; c < 2; ++c)
      x[r*2+c] = ldf<ISBF>(M, bt*64 + (rb*2+r)*8 + cb*2 + c);
  float* bo = blocks + bt*64 + i*4;
  #pragma unroll
  for (int j = 0; j < 4; ++j) bo[j] = x[j];
  float* o = qkv_blk + (i*BT + bt) * 12;
  #pragma unroll
  for (int c = 0; c < 12; ++c) {
    float a = ldf<ISBF>(bqkv_blk, i*12 + c);
    #pragma unroll
    for (int j = 0; j < 4; ++j) a += ldf<ISBF>(Wqkv_blk, i*48 + c*4 + j) * x[j];
    o[c] = a;
  }
}

// ---------- K2: per-block attention, 8 waves key-split in-block, LDS merge ----------
template <bool ISBF>
__global__ void __launch_bounds__(512) k_blk_part(
    const float* __restrict__ qkv_blk,
    const void* __restrict__ Wo_blk,
    const void* __restrict__ bo_blk,
    const int* __restrict__ flags,
    float* __restrict__ all_blocks) {
  if ((bool)flags[0] != ISBF) return;
  __shared__ float red[64*49];       // [ql][wv*6+c], stride 49 (odd -> conflict-free)
  int bid = blockIdx.x;              // grid 1024 = 16i * 4b * 16qt
  int qt = bid & 15, b = (bid >> 4) & 3, i = bid >> 6;
  int tid = threadIdx.x;
  int wv = __builtin_amdgcn_readfirstlane(tid) >> 6;   // wave id 0..7 in SGPR
  int ql = tid & 63;
  const float* base = qkv_blk + (size_t)(i*BT + b*TT) * 12;
  int q = qt*64 + ql;
  const float* qr = base + q*12;
  const float S2 = 0.70710678f;      // 1/sqrt(Dh=2)
  float q00 = qr[0]*S2, q01 = qr[1]*S2;   // head 0
  float q10 = qr[2]*S2, q11 = qr[3]*S2;   // head 1
  float l0=0.f, l1=0.f, a00=0.f, a01=0.f, a10=0.f, a11=0.f;
  int kbeg = wv*128;
  #pragma unroll 4
  for (int k = kbeg; k < kbeg + 128; ++k) {
    const float* kr = base + k*12 + 4;    // uniform address -> s_load_dwordx8
    float k0=kr[0], k1=kr[1], k2=kr[2], k3=kr[3];
    float v0=kr[4], v1=kr[5], v2=kr[6], v3=kr[7];
    float p0 = __expf(q00*k0 + q01*k1);
    float p1 = __expf(q10*k2 + q11*k3);
    l0 += p0; a00 += p0*v0; a01 += p0*v1;
    l1 += p1; a10 += p1*v2; a11 += p1*v3;
  }
  float* rr = red + ql*49 + wv*6;
  rr[0]=l0; rr[1]=l1; rr[2]=a00; rr[3]=a01; rr[4]=a10; rr[5]=a11;
  __syncthreads();
  if (tid < 64) {
    float s[6] = {0.f,0.f,0.f,0.f,0.f,0.f};
    #pragma unroll
    for (int w = 0; w < 8; ++w) {
      const float* p = red + tid*49 + w*6;
      #pragma unroll
      for (int c = 0; c < 6; ++c) s[c] += p[c];
    }
    float r0 = rcpf(s[0]), r1 = rcpf(s[1]);
    float o[4] = { s[2]*r0, s[3]*r0, s[4]*r1, s[5]*r1 };
    int q2 = qt*64 + tid;
    float* outp = all_blocks + (size_t)(b*TT + q2)*64 + i*4;
    #pragma unroll
    for (int j = 0; j < 4; ++j) {
      float a = ldf<ISBF>(bo_blk, i*4 + j);
      #pragma unroll
      for (int m2 = 0; m2 < 4; ++m2) a += ldf<ISBF>(Wo_blk, i*16 + j*4 + m2) * o[m2];
      outp[j] = a;
    }
  }
}

// ---------- K3: cross QKV projection (64 -> 192) ----------
template <bool ISBF>
__global__ void __launch_bounds__(256) k_qkv_c(
    const float* __restrict__ all_blocks,
    const void* __restrict__ Wqkv_c,
    const void* __restrict__ bqkv_c,
    const int* __restrict__ flags,
    float* __restrict__ qkv_c) {
  if ((bool)flags[0] != ISBF) return;
  __shared__ float xs[8*64];
  int t0 = blockIdx.x * 8;         // grid 512
  for (int idx = threadIdx.x; idx < 512; idx += 256)
    xs[idx] = all_blocks[t0*64 + idx];
  __syncthreads();
  int tok = threadIdx.x >> 5, lane32 = threadIdx.x & 31;
  const float* x = xs + tok*64;
  #pragma unroll
  for (int kk = 0; kk < 6; ++kk) {
    int c = kk*32 + lane32;
    float a = ldf<ISBF>(bqkv_c, c);
    #pragma unroll
    for (int j = 0; j < 64; j += 8) a += dot8<ISBF>(Wqkv_c, c*64 + j, x + j);
    qkv_c[(t0 + tok)*192 + c] = a;
  }
}

// ---------- K4: cross attention, 8 waves key-split in-block, LDS merge, no atomics ----------
__global__ void __launch_bounds__(512) k_cross3(
    const float* __restrict__ qkv_c,
    float* __restrict__ l_c, float* __restrict__ acc_c) {
  __shared__ float red[64*73];       // [ql][wv*9+c], stride 73 (odd -> conflict-free)
  int bid = blockIdx.x;              // grid 512 = 4b * 8h * 16qt
  int qt = bid & 15, h = (bid >> 4) & 7, b = bid >> 7;
  int tid = threadIdx.x;
  int wv = __builtin_amdgcn_readfirstlane(tid) >> 6;
  int ql = tid & 63;
  const float* base = qkv_c + (size_t)b*TT*192;
  int q = qt*64 + ql;
  float qv[8];
  #pragma unroll
  for (int c = 0; c < 8; ++c) qv[c] = base[q*192 + h*8 + c] * 0.35355339f; // 1/sqrt(8)
  float l = 0.f, acc[8];
  #pragma unroll
  for (int c = 0; c < 8; ++c) acc[c] = 0.f;
  int kbeg = wv*128;
  #pragma unroll 2
  for (int k = kbeg; k < kbeg + 128; ++k) {
    const float* kr = base + (size_t)k*192 + 64  + h*8;  // K chans: uniform -> s_load
    const float* vr = base + (size_t)k*192 + 128 + h*8;  // V chans: uniform -> s_load
    float s = 0.f;
    #pragma unroll
    for (int c = 0; c < 8; ++c) s += qv[c] * kr[c];
    float p = __expf(s);
    l += p;
    #pragma unroll
    for (int c = 0; c < 8; ++c) acc[c] += p * vr[c];
  }
  float* rr = red + ql*73 + wv*9;
  rr[0] = l;
  #pragma unroll
  for (int c = 0; c < 8; ++c) rr[1+c] = acc[c];
  __syncthreads();
  if (tid < 64) {
    float ls = 0.f, as[8];
    #pragma unroll
    for (int c = 0; c < 8; ++c) as[c] = 0.f;
    #pragma unroll
    for (int w = 0; w < 8; ++w) {
      const float* p = red + tid*73 + w*9;
      ls += p[0];
      #pragma unroll
      for (int c = 0; c < 8; ++c) as[c] += p[1+c];
    }
    float invl = rcpf(ls);
    int q2 = qt*64 + tid;
    int idx = (b*8 + h)*TT + q2;
    l_c[idx] = ls;
    #pragma unroll
    for (int c = 0; c < 8; ++c) acc_c[idx*8 + c] = as[c] * invl;   // normalized PV
  }
}

// ---------- K5: Wo_c projection on normalized PV, residual, LN1 ----------
template <bool ISBF>
__global__ void __launch_bounds__(256) k_finalize_cross(
    const float* __restrict__ all_blocks,
    const float* __restrict__ acc_c,
    const void* __restrict__ Wo_c, const void* __restrict__ bo_c,
    const void* __restrict__ g1, const void* __restrict__ be1,
    const int* __restrict__ flags,
    float* __restrict__ ln1) {
  if ((bool)flags[0] != ISBF) return;
  __shared__ float pvs[4*64];
  int tt = threadIdx.x >> 6, j = threadIdx.x & 63;  // one token per wave, lane = channel
  int t = blockIdx.x*4 + tt;       // grid 1024
  int b = t >> 10, tl = t & 1023;
  int h = j >> 3;
  int idx = (b*8 + h)*TT + tl;
  pvs[tt*64 + j] = acc_c[idx*8 + (j & 7)];
  __syncthreads();
  float a = ldf<ISBF>(bo_c, j);
  const float* p = pvs + tt*64;
  #pragma unroll
  for (int m = 0; m < 64; m += 8) a += dot8<ISBF>(Wo_c, j*64 + m, p + m);
  float x = all_blocks[t*64 + j] + a;
  float s = x, s2 = x*x;
  #pragma unroll
  for (int off = 32; off; off >>= 1) { s += __shfl_xor(s, off); s2 += __shfl_xor(s2, off); }
  float mu  = s  * (1.f/64.f);
  float var = s2 * (1.f/64.f) - mu*mu;
  float y = (x - mu) * rsqrtf(var + 1e-5f) * ldf<ISBF>(g1, j) + ldf<ISBF>(be1, j);
  ln1[t*64 + j] = y;
}

// ---------- K6: recv transposed — thread owns 4 keys, 32-query slices, 2-way atomic ----------
__global__ void __launch_bounds__(64) k_recv_t2(
    const float* __restrict__ qkv_c,
    const float* __restrict__ l_c,
    float* __restrict__ recv_part) {
  int bid = blockIdx.x;              // grid 4096 = 4b * 8h * 4kt * 32qs
  int qs = bid & 31, kt = (bid >> 5) & 3, h = (bid >> 7) & 7, b = bid >> 10;
  const float* base = qkv_c + (size_t)b*TT*192;
  const float* lrow = l_c + (b*8 + h)*TT;
  float kv[4][8];
  #pragma unroll
  for (int i = 0; i < 4; ++i) {
    int k = kt*256 + i*64 + threadIdx.x;
    #pragma unroll
    for (int c = 0; c < 8; ++c)
      kv[i][c] = base[(size_t)k*192 + 64 + h*8 + c] * 0.35355339f;
  }
  float acc[4] = {0.f, 0.f, 0.f, 0.f};
  #pragma unroll 2
  for (int qq = 0; qq < 32; ++qq) {
    int q = qs*32 + qq;
    const float* qr = base + (size_t)q*192 + h*8;   // uniform -> s_load
    float q0=qr[0],q1=qr[1],q2=qr[2],q3=qr[3],q4=qr[4],q5=qr[5],q6=qr[6],q7=qr[7];
    float invl = rcpf(lrow[q]);                     // uniform load + rcp
    #pragma unroll
    for (int i = 0; i < 4; ++i) {
      float s = q0*kv[i][0] + q1*kv[i][1] + q2*kv[i][2] + q3*kv[i][3]
              + q4*kv[i][4] + q5*kv[i][5] + q6*kv[i][6] + q7*kv[i][7];
      acc[i] += __expf(s) * invl;
    }
  }
  int src = h*16 + (qs >> 1);        // 128 sources; 2 contributors each (commutative)
  #pragma unroll
  for (int i = 0; i < 4; ++i) {
    int k = kt*256 + i*64 + threadIdx.x;
    atomicAdd(recv_part + ((size_t)(b*1024 + k))*128 + src, acc[i]);
  }
}

// ---------- K6b: reduce 128 partials -> attn_recv ----------
__global__ void __launch_bounds__(256) k_recv_reduce(
    const float* __restrict__ recv_part, float* __restrict__ attn_recv) {
  int g = blockIdx.x * 256 + threadIdx.x;   // 4096 = b*1024+k
  const float4* p = (const float4*)(recv_part + (size_t)g*128);
  float s = 0.f;
  #pragma unroll
  for (int i = 0; i < 32; ++i) {
    float4 v = p[i];
    s += v.x + v.y + v.z + v.w;
  }
  attn_recv[g] = s * (1.f/8192.f);          // /(H=8 * T=1024)
}

// ---------- K7: FFN + LN2 + sensitivity gate + un-blocking to 8x8 ----------
template <bool ISBF>
__global__ void __launch_bounds__(256) k_ffn_out(
    const float* __restrict__ ln1,
    const void* __restrict__ W1b, const void* __restrict__ b1b,
    const void* __restrict__ W2b, const void* __restrict__ b2b,
    const void* __restrict__ g2, const void* __restrict__ be2,
    const float* __restrict__ blocks,
    const int* __restrict__ tok32,
    const float* __restrict__ attn_recv,
    const void* __restrict__ sens_emb,
    const void* __restrict__ sens_alpha,
    const int* __restrict__ flags,
    void* __restrict__ out) {
  if ((bool)flags[0] != ISBF) return;
  __shared__ float ld[4*64];
  __shared__ float hbuf[4*256];
  int t0 = blockIdx.x * 4;         // grid 1024, 4 tokens per WG
  ld[threadIdx.x] = ln1[t0*64 + threadIdx.x];
  __syncthreads();
  {
    float acc[4];
    float bb = ldf<ISBF>(b1b, threadIdx.x);
    #pragma unroll
    for (int tt = 0; tt < 4; ++tt) acc[tt] = bb;
    #pragma unroll
    for (int j = 0; j < 64; j += 8) {
      float w[8]; load8<ISBF>(W1b, threadIdx.x*64 + j, w);
      #pragma unroll
      for (int jj = 0; jj < 8; ++jj)
        #pragma unroll
        for (int tt = 0; tt < 4; ++tt) acc[tt] += w[jj] * ld[tt*64 + j + jj];
    }
    #pragma unroll
    for (int tt = 0; tt < 4; ++tt) {
      float v = acc[tt];
      // tanh-GELU in sigmoid form: v * sigmoid(1.5957691*v + 0.07135481*v^3)
      float u = 1.5957691f*v + 0.07135481f*v*v*v;
      hbuf[tt*256 + threadIdx.x] = v * rcpf(1.f + __expf(-u));
    }
  }
  __syncthreads();
  int tt = threadIdx.x >> 6, j = threadIdx.x & 63;   // token per wave, lane = channel
  int t = t0 + tt, b = t >> 10, tl = t & 1023;
  float y = ldf<ISBF>(b2b, j);
  const float* hb = hbuf + tt*256;
  #pragma unroll
  for (int k = 0; k < 256; k += 8) y += dot8<ISBF>(W2b, j*256 + k, hb + k);
  float z = ld[tt*64 + j] + y;
  float s = z, s2 = z*z;
  #pragma unroll
  for (int off = 32; off; off >>= 1) { s += __shfl_xor(s, off); s2 += __shfl_xor(s2, off); }
  float mu  = s  * (1.f/64.f);
  float var = s2 * (1.f/64.f) - mu*mu;
  float y2 = (z - mu) * rsqrtf(var + 1e-5f) * ldf<ISBF>(g2, j) + ldf<ISBF>(be2, j);
  int tok = flags[1] ? tok32[t*2] : tok32[t];
  int i = j >> 2, e = j & 3;
  float recv = attn_recv[b*TT + tl];
  float sv = ldf<ISBF>(sens_emb, tok*16 + i) + recv * ldf<ISBF>(sens_alpha, i);
  float sg = rcpf(1.f + __expf(-sv));
  float blk = blocks[t*64 + j];
  float nb = blk + (y2 - blk) * sg;
  int rb = i >> 2, cb = i & 3, r = e >> 1, c = e & 1;
  int oidx = t*64 + (rb*2 + r)*8 + cb*2 + c;
  if (ISBF) ((__hip_bfloat16*)out)[oidx] = __float2bfloat16(nb);
  else      ((float*)out)[oidx] = nb;
}

extern "C" void kernel_launch(void* const* d_in, const int* in_sizes, int n_in,
                              void* d_out, int out_size, void* d_ws, size_t ws_size,
                              hipStream_t stream) {
  const void* M        = d_in[0];
  const int*  tok      = (const int*)d_in[1];
  const void* Wqkv_blk = d_in[2];
  const void* bqkv_blk = d_in[3];
  const void* Wo_blk   = d_in[4];
  const void* bo_blk   = d_in[5];
  const void* Wqkv_c   = d_in[6];
  const void* bqkv_c   = d_in[7];
  const void* Wo_c     = d_in[8];
  const void* bo_c     = d_in[9];
  const void* W1       = d_in[10];
  const void* b1       = d_in[11];
  const void* W2       = d_in[12];
  const void* b2       = d_in[13];
  const void* g1       = d_in[14];
  const void* be1      = d_in[15];
  const void* g2i      = d_in[16];
  const void* be2      = d_in[17];
  const void* sens_emb = d_in[18];
  const void* sens_al  = d_in[19];

  float* ws = (float*)d_ws;
  float* blocks    = ws + OFF_BLOCKS;
  float* qkv_blk   = ws + OFF_QKVB;
  float* recv_part = ws + OFF_RECVP;   // aliases qkv_blk (dead after k_blk_part)
  float* all_blk   = ws + OFF_ALLB;
  float* qkv_c     = ws + OFF_QKVC;
  float* l_c       = ws + OFF_LC;
  float* acc_c     = ws + OFF_ACCC;
  float* attn_recv = ws + OFF_RECV;
  float* ln1       = ws + OFF_LN1;
  int*   flags     = (int*)(ws + OFF_FLAGS);

  k_detect<<<1, 64, 0, stream>>>(M, tok, flags);
  k_prep<true ><<<256, 256, 0, stream>>>(M, Wqkv_blk, bqkv_blk, flags, blocks, qkv_blk);
  k_prep<false><<<256, 256, 0, stream>>>(M, Wqkv_blk, bqkv_blk, flags, blocks, qkv_blk);
  k_blk_part<true ><<<1024, 512, 0, stream>>>(qkv_blk, Wo_blk, bo_blk, flags, all_blk);
  k_blk_part<false><<<1024, 512, 0, stream>>>(qkv_blk, Wo_blk, bo_blk, flags, all_blk);
  // qkv_blk now dead; zero the recv partial accumulator that aliases it
  hipMemsetAsync(recv_part, 0, (size_t)(4*1024*128) * sizeof(float), stream);
  k_qkv_c<true ><<<512, 256, 0, stream>>>(all_blk, Wqkv_c, bqkv_c, flags, qkv_c);
  k_qkv_c<false><<<512, 256, 0, stream>>>(all_blk, Wqkv_c, bqkv_c, flags, qkv_c);
  k_cross3<<<512, 512, 0, stream>>>(qkv_c, l_c, acc_c);
  k_finalize_cross<true ><<<1024, 256, 0, stream>>>(all_blk, acc_c, Wo_c, bo_c, g1, be1, flags, ln1);
  k_finalize_cross<false><<<1024, 256, 0, stream>>>(all_blk, acc_c, Wo_c, bo_c, g1, be1, flags, ln1);
  k_recv_t2<<<4096, 64, 0, stream>>>(qkv_c, l_c, recv_part);
  k_recv_reduce<<<16, 256, 0, stream>>>(recv_part, attn_recv);
  k_ffn_out<true ><<<1024, 256, 0, stream>>>(ln1, W1, b1, W2, b2, g2i, be2,
                                             blocks, tok, attn_recv, sens_emb, sens_al,
                                             flags, (void*)d_out);
  k_ffn_out<false><<<1024, 256, 0, stream>>>(ln1, W1, b1, W2, b2, g2i, be2,
                                             blocks, tok, attn_recv, sens_emb, sens_al,
                                             flags, (void*)d_out);
}

// Round 7
// 270.940 us; speedup vs baseline: 1.9450x; 1.1460x over previous
//
#include <hip/hip_runtime.h>
#include <hip/hip_bf16.h>
#include <math.h>

// Problem constants (setup_inputs: B=4, T=1024)
#define BB 4
#define TT 1024
#define BT 4096

// Workspace layout (fp32 offsets in floats)
#define OFF_BLOCKS 0          // [BT][64]  blocks in [i*4+e] channel order
#define OFF_QKVB   262144     // [16][BT][12] per-block qkv (dead after k_blk_part)
#define OFF_RECVP  262144     // [B][128 src][1024 k] recv partials (aliases QKVB, 2 MB)
#define OFF_ALLB   1048576    // [BT][64]  per-block MHA output (all_blocks)
#define OFF_QKVC   1310720    // [BT][192] cross qkv
#define OFF_LC     2097152    // [B*8][T]  cross softmax denominators (unnormalized)
#define OFF_ACCC   2129920    // [B*8][T][8] cross PV (normalized by l)
#define OFF_RECV   2392064    // [B][T]    attention-received column means
#define OFF_LN1    2396160    // [BT][64]  post-LN1 activations
#define OFF_FLAGS  2658304    // [16] ints: [0]=floats-are-bf16, [1]=tokens-are-int64
#define WS_FLOATS  2658320

__device__ inline float rcpf(float x) { return __builtin_amdgcn_rcpf(x); }

// ---------- dtype-templated load helpers (single path per instantiation) ----------
template <bool ISBF>
__device__ inline float ldf(const void* p, int i) {
  if (ISBF) return __bfloat162float(((const __hip_bfloat16*)p)[i]);
  else      return ((const float*)p)[i];
}

template <bool ISBF>
__device__ inline void load8(const void* p, int off, float* w) {
  if (ISBF) {
    uint4 u = *reinterpret_cast<const uint4*>((const __hip_bfloat16*)p + off);
    w[0] = __uint_as_float(u.x << 16); w[1] = __uint_as_float(u.x & 0xffff0000u);
    w[2] = __uint_as_float(u.y << 16); w[3] = __uint_as_float(u.y & 0xffff0000u);
    w[4] = __uint_as_float(u.z << 16); w[5] = __uint_as_float(u.z & 0xffff0000u);
    w[6] = __uint_as_float(u.w << 16); w[7] = __uint_as_float(u.w & 0xffff0000u);
  } else {
    const float4* f = (const float4*)((const float*)p + off);
    float4 a = f[0], b = f[1];
    w[0]=a.x; w[1]=a.y; w[2]=a.z; w[3]=a.w; w[4]=b.x; w[5]=b.y; w[6]=b.z; w[7]=b.w;
  }
}

template <bool ISBF>
__device__ inline float dot8(const void* W, int off, const float* x) {
  float w[8]; load8<ISBF>(W, off, w);
  return w[0]*x[0] + w[1]*x[1] + w[2]*x[2] + w[3]*x[3]
       + w[4]*x[4] + w[5]*x[5] + w[6]*x[6] + w[7]*x[7];
}

// ---------- K0: dtype detection ----------
__global__ void __launch_bounds__(64) k_detect(
    const void* __restrict__ M, const int* __restrict__ tok, int* __restrict__ flags) {
  const unsigned short* h = (const unsigned short*)M;
  unsigned short v = h[threadIdx.x];
  int e = (v >> 7) & 0xff;
  bool pass = (e >= 90) && (e <= 141);
  unsigned long long m = __ballot(pass);
  if (threadIdx.x == 0) {
    flags[0] = (__popcll(m) >= 58) ? 1 : 0;
    flags[1] = ((tok[1] | tok[3] | tok[5] | tok[7]) == 0) ? 1 : 0;
  }
}

// ---------- K1: blocks gather + per-block QKV ----------
template <bool ISBF>
__global__ void __launch_bounds__(256) k_prep(
    const void* __restrict__ M,
    const void* __restrict__ Wqkv_blk,
    const void* __restrict__ bqkv_blk,
    const int* __restrict__ flags,
    float* __restrict__ blocks, float* __restrict__ qkv_blk) {
  if ((bool)flags[0] != ISBF) return;
  int g = blockIdx.x * 256 + threadIdx.x;        // 65536 = 16 blocks * 4096 tokens
  int i = g >> 12, bt = g & 4095;
  int rb = i >> 2, cb = i & 3;
  float x[4];
  #pragma unroll
  for (int r = 0; r < 2; ++r)
    #pragma unroll
    for (int c = 0; c < 2; ++c)
      x[r*2+c] = ldf<ISBF>(M, bt*64 + (rb*2+r)*8 + cb*2 + c);
  float* bo = blocks + bt*64 + i*4;
  #pragma unroll
  for (int j = 0; j < 4; ++j) bo[j] = x[j];
  float* o = qkv_blk + (i*BT + bt) * 12;
  #pragma unroll
  for (int c = 0; c < 12; ++c) {
    float a = ldf<ISBF>(bqkv_blk, i*12 + c);
    #pragma unroll
    for (int j = 0; j < 4; ++j) a += ldf<ISBF>(Wqkv_blk, i*48 + c*4 + j) * x[j];
    o[c] = a;
  }
}

// ---------- K2: per-block attention, 8 waves key-split in-block, LDS merge ----------
template <bool ISBF>
__global__ void __launch_bounds__(512) k_blk_part(
    const float* __restrict__ qkv_blk,
    const void* __restrict__ Wo_blk,
    const void* __restrict__ bo_blk,
    const int* __restrict__ flags,
    float* __restrict__ all_blocks) {
  if ((bool)flags[0] != ISBF) return;
  __shared__ float red[64*49];       // [ql][wv*6+c], stride 49 (odd -> conflict-free)
  int bid = blockIdx.x;              // grid 1024 = 16i * 4b * 16qt
  int qt = bid & 15, b = (bid >> 4) & 3, i = bid >> 6;
  int tid = threadIdx.x;
  int wv = __builtin_amdgcn_readfirstlane(tid) >> 6;   // wave id 0..7 in SGPR
  int ql = tid & 63;
  const float* base = qkv_blk + (size_t)(i*BT + b*TT) * 12;
  int q = qt*64 + ql;
  const float* qr = base + q*12;
  const float S2 = 0.70710678f;      // 1/sqrt(Dh=2)
  float q00 = qr[0]*S2, q01 = qr[1]*S2;   // head 0
  float q10 = qr[2]*S2, q11 = qr[3]*S2;   // head 1
  float l0=0.f, l1=0.f, a00=0.f, a01=0.f, a10=0.f, a11=0.f;
  int kbeg = wv*128;
  #pragma unroll 4
  for (int k = kbeg; k < kbeg + 128; ++k) {
    const float* kr = base + k*12 + 4;    // uniform address -> s_load_dwordx8
    float k0=kr[0], k1=kr[1], k2=kr[2], k3=kr[3];
    float v0=kr[4], v1=kr[5], v2=kr[6], v3=kr[7];
    float p0 = __expf(q00*k0 + q01*k1);
    float p1 = __expf(q10*k2 + q11*k3);
    l0 += p0; a00 += p0*v0; a01 += p0*v1;
    l1 += p1; a10 += p1*v2; a11 += p1*v3;
  }
  float* rr = red + ql*49 + wv*6;
  rr[0]=l0; rr[1]=l1; rr[2]=a00; rr[3]=a01; rr[4]=a10; rr[5]=a11;
  __syncthreads();
  if (tid < 64) {
    float s[6] = {0.f,0.f,0.f,0.f,0.f,0.f};
    #pragma unroll
    for (int w = 0; w < 8; ++w) {
      const float* p = red + tid*49 + w*6;
      #pragma unroll
      for (int c = 0; c < 6; ++c) s[c] += p[c];
    }
    float r0 = rcpf(s[0]), r1 = rcpf(s[1]);
    float o[4] = { s[2]*r0, s[3]*r0, s[4]*r1, s[5]*r1 };
    int q2 = qt*64 + tid;
    float* outp = all_blocks + (size_t)(b*TT + q2)*64 + i*4;
    #pragma unroll
    for (int j = 0; j < 4; ++j) {
      float a = ldf<ISBF>(bo_blk, i*4 + j);
      #pragma unroll
      for (int m2 = 0; m2 < 4; ++m2) a += ldf<ISBF>(Wo_blk, i*16 + j*4 + m2) * o[m2];
      outp[j] = a;
    }
  }
}

// ---------- K3: cross QKV projection (64 -> 192) ----------
template <bool ISBF>
__global__ void __launch_bounds__(256) k_qkv_c(
    const float* __restrict__ all_blocks,
    const void* __restrict__ Wqkv_c,
    const void* __restrict__ bqkv_c,
    const int* __restrict__ flags,
    float* __restrict__ qkv_c) {
  if ((bool)flags[0] != ISBF) return;
  __shared__ float xs[8*64];
  int t0 = blockIdx.x * 8;         // grid 512
  for (int idx = threadIdx.x; idx < 512; idx += 256)
    xs[idx] = all_blocks[t0*64 + idx];
  __syncthreads();
  int tok = threadIdx.x >> 5, lane32 = threadIdx.x & 31;
  const float* x = xs + tok*64;
  #pragma unroll
  for (int kk = 0; kk < 6; ++kk) {
    int c = kk*32 + lane32;
    float a = ldf<ISBF>(bqkv_c, c);
    #pragma unroll
    for (int j = 0; j < 64; j += 8) a += dot8<ISBF>(Wqkv_c, c*64 + j, x + j);
    qkv_c[(t0 + tok)*192 + c] = a;
  }
}

// ---------- K4: cross attention, 8 waves key-split in-block, LDS merge, no atomics ----------
__global__ void __launch_bounds__(512) k_cross3(
    const float* __restrict__ qkv_c,
    float* __restrict__ l_c, float* __restrict__ acc_c) {
  __shared__ float red[64*73];       // [ql][wv*9+c], stride 73 (odd -> conflict-free)
  int bid = blockIdx.x;              // grid 512 = 4b * 8h * 16qt
  int qt = bid & 15, h = (bid >> 4) & 7, b = bid >> 7;
  int tid = threadIdx.x;
  int wv = __builtin_amdgcn_readfirstlane(tid) >> 6;
  int ql = tid & 63;
  const float* base = qkv_c + (size_t)b*TT*192;
  int q = qt*64 + ql;
  float qv[8];
  #pragma unroll
  for (int c = 0; c < 8; ++c) qv[c] = base[q*192 + h*8 + c] * 0.35355339f; // 1/sqrt(8)
  float l = 0.f, acc[8];
  #pragma unroll
  for (int c = 0; c < 8; ++c) acc[c] = 0.f;
  int kbeg = wv*128;
  #pragma unroll 2
  for (int k = kbeg; k < kbeg + 128; ++k) {
    const float* kr = base + (size_t)k*192 + 64  + h*8;  // K chans: uniform -> s_load
    const float* vr = base + (size_t)k*192 + 128 + h*8;  // V chans: uniform -> s_load
    float s = 0.f;
    #pragma unroll
    for (int c = 0; c < 8; ++c) s += qv[c] * kr[c];
    float p = __expf(s);
    l += p;
    #pragma unroll
    for (int c = 0; c < 8; ++c) acc[c] += p * vr[c];
  }
  float* rr = red + ql*73 + wv*9;
  rr[0] = l;
  #pragma unroll
  for (int c = 0; c < 8; ++c) rr[1+c] = acc[c];
  __syncthreads();
  if (tid < 64) {
    float ls = 0.f, as[8];
    #pragma unroll
    for (int c = 0; c < 8; ++c) as[c] = 0.f;
    #pragma unroll
    for (int w = 0; w < 8; ++w) {
      const float* p = red + tid*73 + w*9;
      ls += p[0];
      #pragma unroll
      for (int c = 0; c < 8; ++c) as[c] += p[1+c];
    }
    float invl = rcpf(ls);
    int q2 = qt*64 + tid;
    int idx = (b*8 + h)*TT + q2;
    l_c[idx] = ls;
    #pragma unroll
    for (int c = 0; c < 8; ++c) acc_c[idx*8 + c] = as[c] * invl;   // normalized PV
  }
}

// ---------- K5: Wo_c projection on normalized PV, residual, LN1 ----------
template <bool ISBF>
__global__ void __launch_bounds__(256) k_finalize_cross(
    const float* __restrict__ all_blocks,
    const float* __restrict__ acc_c,
    const void* __restrict__ Wo_c, const void* __restrict__ bo_c,
    const void* __restrict__ g1, const void* __restrict__ be1,
    const int* __restrict__ flags,
    float* __restrict__ ln1) {
  if ((bool)flags[0] != ISBF) return;
  __shared__ float pvs[4*64];
  int tt = threadIdx.x >> 6, j = threadIdx.x & 63;  // one token per wave, lane = channel
  int t = blockIdx.x*4 + tt;       // grid 1024
  int b = t >> 10, tl = t & 1023;
  int h = j >> 3;
  int idx = (b*8 + h)*TT + tl;
  pvs[tt*64 + j] = acc_c[idx*8 + (j & 7)];
  __syncthreads();
  float a = ldf<ISBF>(bo_c, j);
  const float* p = pvs + tt*64;
  #pragma unroll
  for (int m = 0; m < 64; m += 8) a += dot8<ISBF>(Wo_c, j*64 + m, p + m);
  float x = all_blocks[t*64 + j] + a;
  float s = x, s2 = x*x;
  #pragma unroll
  for (int off = 32; off; off >>= 1) { s += __shfl_xor(s, off); s2 += __shfl_xor(s2, off); }
  float mu  = s  * (1.f/64.f);
  float var = s2 * (1.f/64.f) - mu*mu;
  float y = (x - mu) * rsqrtf(var + 1e-5f) * ldf<ISBF>(g1, j) + ldf<ISBF>(be1, j);
  ln1[t*64 + j] = y;
}

// ---------- K6: recv — thread owns 2 keys, write-once coalesced partials, no atomics ----------
__global__ void __launch_bounds__(64) k_recv_t3(
    const float* __restrict__ qkv_c,
    const float* __restrict__ l_c,
    float* __restrict__ recv_part) {
  int bid = blockIdx.x;              // grid 4096 = 4b * 8h * 8kt * 16qs
  int qs = bid & 15, kt = (bid >> 4) & 7, h = (bid >> 7) & 7, b = bid >> 10;
  const float* base = qkv_c + (size_t)b*TT*192;
  const float* lrow = l_c + (b*8 + h)*TT;
  int ql = threadIdx.x;
  int k1 = kt*128 + ql, k2 = k1 + 64;
  float kv1[8], kv2[8];
  #pragma unroll
  for (int c = 0; c < 8; ++c) {
    kv1[c] = base[(size_t)k1*192 + 64 + h*8 + c] * 0.35355339f;
    kv2[c] = base[(size_t)k2*192 + 64 + h*8 + c] * 0.35355339f;
  }
  float acc1 = 0.f, acc2 = 0.f;
  #pragma unroll 4
  for (int qq = 0; qq < 64; ++qq) {
    int q = qs*64 + qq;
    const float* qr = base + (size_t)q*192 + h*8;   // uniform -> s_load
    float q0=qr[0],q1=qr[1],q2=qr[2],q3=qr[3],q4=qr[4],q5=qr[5],q6=qr[6],q7=qr[7];
    float invl = rcpf(lrow[q]);                     // uniform load + rcp
    float s1 = q0*kv1[0]+q1*kv1[1]+q2*kv1[2]+q3*kv1[3]
             + q4*kv1[4]+q5*kv1[5]+q6*kv1[6]+q7*kv1[7];
    float s2 = q0*kv2[0]+q1*kv2[1]+q2*kv2[2]+q3*kv2[3]
             + q4*kv2[4]+q5*kv2[5]+q6*kv2[6]+q7*kv2[7];
    acc1 += __expf(s1) * invl;
    acc2 += __expf(s2) * invl;
  }
  // layout [b][src][k]: lanes store consecutive k -> coalesced; every slot written once
  float* rp = recv_part + ((size_t)(b*128 + h*16 + qs)) * 1024;
  rp[k1] = acc1;
  rp[k2] = acc2;
}

// ---------- K6b: reduce 128 src partials -> attn_recv ----------
__global__ void __launch_bounds__(256) k_recv_reduce(
    const float* __restrict__ recv_part, float* __restrict__ attn_recv) {
  int g = blockIdx.x * 256 + threadIdx.x;   // 4096 = b*1024+k
  int b = g >> 10, k = g & 1023;
  const float* p = recv_part + (size_t)b*128*1024 + k;
  float s = 0.f;
  #pragma unroll 8
  for (int src = 0; src < 128; ++src) s += p[(size_t)src*1024];  // lanes coalesced per src
  attn_recv[g] = s * (1.f/8192.f);          // /(H=8 * T=1024)
}

// ---------- K7: FFN + LN2 + sensitivity gate + un-blocking to 8x8 ----------
template <bool ISBF>
__global__ void __launch_bounds__(256) k_ffn_out(
    const float* __restrict__ ln1,
    const void* __restrict__ W1b, const void* __restrict__ b1b,
    const void* __restrict__ W2b, const void* __restrict__ b2b,
    const void* __restrict__ g2, const void* __restrict__ be2,
    const float* __restrict__ blocks,
    const int* __restrict__ tok32,
    const float* __restrict__ attn_recv,
    const void* __restrict__ sens_emb,
    const void* __restrict__ sens_alpha,
    const int* __restrict__ flags,
    void* __restrict__ out) {
  if ((bool)flags[0] != ISBF) return;
  __shared__ float ld[4*64];
  __shared__ float hbuf[4*256];
  int t0 = blockIdx.x * 4;         // grid 1024, 4 tokens per WG
  ld[threadIdx.x] = ln1[t0*64 + threadIdx.x];
  __syncthreads();
  {
    float acc[4];
    float bb = ldf<ISBF>(b1b, threadIdx.x);
    #pragma unroll
    for (int tt = 0; tt < 4; ++tt) acc[tt] = bb;
    #pragma unroll
    for (int j = 0; j < 64; j += 8) {
      float w[8]; load8<ISBF>(W1b, threadIdx.x*64 + j, w);
      #pragma unroll
      for (int jj = 0; jj < 8; ++jj)
        #pragma unroll
        for (int tt = 0; tt < 4; ++tt) acc[tt] += w[jj] * ld[tt*64 + j + jj];
    }
    #pragma unroll
    for (int tt = 0; tt < 4; ++tt) {
      float v = acc[tt];
      // tanh-GELU in sigmoid form: v * sigmoid(1.5957691*v + 0.07135481*v^3)
      float u = 1.5957691f*v + 0.07135481f*v*v*v;
      hbuf[tt*256 + threadIdx.x] = v * rcpf(1.f + __expf(-u));
    }
  }
  __syncthreads();
  int tt = threadIdx.x >> 6, j = threadIdx.x & 63;   // token per wave, lane = channel
  int t = t0 + tt, b = t >> 10, tl = t & 1023;
  float y = ldf<ISBF>(b2b, j);
  const float* hb = hbuf + tt*256;
  #pragma unroll
  for (int k = 0; k < 256; k += 8) y += dot8<ISBF>(W2b, j*256 + k, hb + k);
  float z = ld[tt*64 + j] + y;
  float s = z, s2 = z*z;
  #pragma unroll
  for (int off = 32; off; off >>= 1) { s += __shfl_xor(s, off); s2 += __shfl_xor(s2, off); }
  float mu  = s  * (1.f/64.f);
  float var = s2 * (1.f/64.f) - mu*mu;
  float y2 = (z - mu) * rsqrtf(var + 1e-5f) * ldf<ISBF>(g2, j) + ldf<ISBF>(be2, j);
  int tok = flags[1] ? tok32[t*2] : tok32[t];
  int i = j >> 2, e = j & 3;
  float recv = attn_recv[b*TT + tl];
  float sv = ldf<ISBF>(sens_emb, tok*16 + i) + recv * ldf<ISBF>(sens_alpha, i);
  float sg = rcpf(1.f + __expf(-sv));
  float blk = blocks[t*64 + j];
  float nb = blk + (y2 - blk) * sg;
  int rb = i >> 2, cb = i & 3, r = e >> 1, c = e & 1;
  int oidx = t*64 + (rb*2 + r)*8 + cb*2 + c;
  if (ISBF) ((__hip_bfloat16*)out)[oidx] = __float2bfloat16(nb);
  else      ((float*)out)[oidx] = nb;
}

extern "C" void kernel_launch(void* const* d_in, const int* in_sizes, int n_in,
                              void* d_out, int out_size, void* d_ws, size_t ws_size,
                              hipStream_t stream) {
  const void* M        = d_in[0];
  const int*  tok      = (const int*)d_in[1];
  const void* Wqkv_blk = d_in[2];
  const void* bqkv_blk = d_in[3];
  const void* Wo_blk   = d_in[4];
  const void* bo_blk   = d_in[5];
  const void* Wqkv_c   = d_in[6];
  const void* bqkv_c   = d_in[7];
  const void* Wo_c     = d_in[8];
  const void* bo_c     = d_in[9];
  const void* W1       = d_in[10];
  const void* b1       = d_in[11];
  const void* W2       = d_in[12];
  const void* b2       = d_in[13];
  const void* g1       = d_in[14];
  const void* be1      = d_in[15];
  const void* g2i      = d_in[16];
  const void* be2      = d_in[17];
  const void* sens_emb = d_in[18];
  const void* sens_al  = d_in[19];

  float* ws = (float*)d_ws;
  float* blocks    = ws + OFF_BLOCKS;
  float* qkv_blk   = ws + OFF_QKVB;
  float* recv_part = ws + OFF_RECVP;   // aliases qkv_blk (dead after k_blk_part)
  float* all_blk   = ws + OFF_ALLB;
  float* qkv_c     = ws + OFF_QKVC;
  float* l_c       = ws + OFF_LC;
  float* acc_c     = ws + OFF_ACCC;
  float* attn_recv = ws + OFF_RECV;
  float* ln1       = ws + OFF_LN1;
  int*   flags     = (int*)(ws + OFF_FLAGS);

  k_detect<<<1, 64, 0, stream>>>(M, tok, flags);
  k_prep<true ><<<256, 256, 0, stream>>>(M, Wqkv_blk, bqkv_blk, flags, blocks, qkv_blk);
  k_prep<false><<<256, 256, 0, stream>>>(M, Wqkv_blk, bqkv_blk, flags, blocks, qkv_blk);
  k_blk_part<true ><<<1024, 512, 0, stream>>>(qkv_blk, Wo_blk, bo_blk, flags, all_blk);
  k_blk_part<false><<<1024, 512, 0, stream>>>(qkv_blk, Wo_blk, bo_blk, flags, all_blk);
  k_qkv_c<true ><<<512, 256, 0, stream>>>(all_blk, Wqkv_c, bqkv_c, flags, qkv_c);
  k_qkv_c<false><<<512, 256, 0, stream>>>(all_blk, Wqkv_c, bqkv_c, flags, qkv_c);
  k_cross3<<<512, 512, 0, stream>>>(qkv_c, l_c, acc_c);
  k_finalize_cross<true ><<<1024, 256, 0, stream>>>(all_blk, acc_c, Wo_c, bo_c, g1, be1, flags, ln1);
  k_finalize_cross<false><<<1024, 256, 0, stream>>>(all_blk, acc_c, Wo_c, bo_c, g1, be1, flags, ln1);
  k_recv_t3<<<4096, 64, 0, stream>>>(qkv_c, l_c, recv_part);
  k_recv_reduce<<<16, 256, 0, stream>>>(recv_part, attn_recv);
  k_ffn_out<true ><<<1024, 256, 0, stream>>>(ln1, W1, b1, W2, b2, g2i, be2,
                                             blocks, tok, attn_recv, sens_emb, sens_al,
                                             flags, (void*)d_out);
  k_ffn_out<false><<<1024, 256, 0, stream>>>(ln1, W1, b1, W2, b2, g2i, be2,
                                             blocks, tok, attn_recv, sens_emb, sens_al,
                                             flags, (void*)d_out);
}